// Round 1
// baseline (888.356 us; speedup 1.0000x reference)
//
#include <hip/hip_runtime.h>
#include <hip/hip_bf16.h>
#include <math.h>

#define D_ 128
#define INV_SQRT_D 0.08838834764831845f

typedef __bf16 bf16x8 __attribute__((ext_vector_type(8)));
typedef __bf16 bf16x2 __attribute__((ext_vector_type(2)));
typedef float f32x4 __attribute__((ext_vector_type(4)));

struct W6 { const float* p[6]; };

// ---------------- weight f32 -> bf16 ----------------
__global__ __launch_bounds__(256) void cvt_weights(W6 w, __bf16* __restrict__ out) {
    int idx = blockIdx.x * 256 + threadIdx.x;
    if (idx >= 6 * 16384) return;
    out[idx] = (__bf16)w.p[idx >> 14][idx & 16383];
}

// ---------------- GEMM: Y = X[gidx] @ W^T  (W row-major (out,in), bf16) ----------------
// per block: 64 rows; per wave: 16 rows x 128 cols via 16x16x32 MFMA
__global__ __launch_bounds__(256) void gemm_xwt(const float* __restrict__ X,
                                                const int* __restrict__ gidx,
                                                const __bf16* __restrict__ Wb,
                                                __bf16* __restrict__ Y, int rows) {
    int lane = threadIdx.x & 63;
    int wave = threadIdx.x >> 6;
    int row0 = blockIdx.x * 64 + wave * 16;
    if (row0 >= rows) return;
    int l16 = lane & 15, kh = lane >> 4;
    int ar = row0 + l16;
    int arc = ar < rows ? ar : rows - 1;
    long srcrow = gidx ? (long)gidx[arc] : (long)arc;
    const float* arow = X + (size_t)srcrow * D_;

    f32x4 acc[8] = {};
#pragma unroll
    for (int k0 = 0; k0 < D_; k0 += 32) {
        int kk = k0 + kh * 8;
        float4 a0 = *(const float4*)(arow + kk);
        float4 a1 = *(const float4*)(arow + kk + 4);
        bf16x8 af;
        af[0] = (__bf16)a0.x; af[1] = (__bf16)a0.y; af[2] = (__bf16)a0.z; af[3] = (__bf16)a0.w;
        af[4] = (__bf16)a1.x; af[5] = (__bf16)a1.y; af[6] = (__bf16)a1.z; af[7] = (__bf16)a1.w;
#pragma unroll
        for (int cb = 0; cb < 8; cb++) {
            bf16x8 bf = *(const bf16x8*)(Wb + (size_t)(cb * 16 + l16) * D_ + kk);
            acc[cb] = __builtin_amdgcn_mfma_f32_16x16x32_bf16(af, bf, acc[cb], 0, 0, 0);
        }
    }
#pragma unroll
    for (int cb = 0; cb < 8; cb++) {
#pragma unroll
        for (int j = 0; j < 4; j++) {
            int r = row0 + kh * 4 + j;
            if (r < rows) Y[(size_t)r * D_ + cb * 16 + l16] = (__bf16)acc[cb][j];
        }
    }
}

// ---------------- CSR build ----------------
__global__ __launch_bounds__(256) void hist2(const int* __restrict__ eu, const int* __restrict__ ei,
                                             int* __restrict__ ucnt, int* __restrict__ icnt, int E) {
    int e = blockIdx.x * 256 + threadIdx.x;
    if (e < E) {
        atomicAdd(&ucnt[eu[e]], 1);
        atomicAdd(&icnt[ei[e]], 1);
    }
}

// single-block chunked exclusive scan; off[n] = total; pos = copy of off
__global__ __launch_bounds__(256) void scan_pos(const int* __restrict__ cnt, int* __restrict__ off,
                                                int* __restrict__ pos, int n) {
    __shared__ int wsum[4];
    __shared__ int run_s;
    int t = threadIdx.x, lane = t & 63, w = t >> 6;
    if (t == 0) run_s = 0;
    __syncthreads();
    const int CH = 16, TILE = 256 * CH;
    for (int base = 0; base < n; base += TILE) {
        int loc[CH];
        int tot = 0;
        int i0 = base + t * CH;
#pragma unroll
        for (int j = 0; j < CH; j++) {
            int v = (i0 + j < n) ? cnt[i0 + j] : 0;
            loc[j] = tot; tot += v;
        }
        int x = tot;
#pragma unroll
        for (int d = 1; d < 64; d <<= 1) {
            int y = __shfl_up(x, d);
            if (lane >= d) x += y;
        }
        if (lane == 63) wsum[w] = x;
        __syncthreads();
        int wbase = 0;
        for (int ww = 0; ww < w; ww++) wbase += wsum[ww];
        int excl = run_s + wbase + x - tot;
#pragma unroll
        for (int j = 0; j < CH; j++) {
            if (i0 + j < n) { off[i0 + j] = excl + loc[j]; pos[i0 + j] = excl + loc[j]; }
        }
        __syncthreads();
        if (t == 255) run_s += wbase + x;
        __syncthreads();
    }
    if (t == 0) off[n] = run_s;
}

__global__ __launch_bounds__(256) void scatter2(const int* __restrict__ eu, const int* __restrict__ ei,
                                                int* __restrict__ upos, int* __restrict__ ipos,
                                                int* __restrict__ ulist, int* __restrict__ ilist, int E) {
    int e = blockIdx.x * 256 + threadIdx.x;
    if (e < E) {
        int pu = atomicAdd(&upos[eu[e]], 1);
        ulist[pu] = e;
        int pi = atomicAdd(&ipos[ei[e]], 1);
        ilist[pi] = e;
    }
}

// ---------------- per-edge logits (one wave per edge) ----------------
__global__ __launch_bounds__(256) void edge_dots(const __bf16* __restrict__ um, const __bf16* __restrict__ im,
                                                 const __bf16* __restrict__ li, const __bf16* __restrict__ lu,
                                                 const float* __restrict__ pV, const float* __restrict__ pK,
                                                 const int* __restrict__ eu, const int* __restrict__ ei,
                                                 const int* __restrict__ rui, const int* __restrict__ riu,
                                                 float* __restrict__ e_ui, float* __restrict__ e_iu,
                                                 float* __restrict__ a_log, float* __restrict__ b_log, int E) {
    int e = blockIdx.x * 4 + (threadIdx.x >> 6);
    if (e >= E) return;
    int lane = threadIdx.x & 63;
    int u = eu[e], it = ei[e];
    bf16x2 umv = ((const bf16x2*)(um + (size_t)u * D_))[lane];
    bf16x2 imv = ((const bf16x2*)(im + (size_t)it * D_))[lane];
    bf16x2 liv = ((const bf16x2*)(li + (size_t)u * D_))[lane];
    bf16x2 luv = ((const bf16x2*)(lu + (size_t)u * D_))[lane];
    float2 pv = ((const float2*)(pV + (size_t)rui[e] * D_))[lane];
    float2 pk = ((const float2*)(pK + (size_t)riu[e] * D_))[lane];
    float um0 = (float)umv[0], um1 = (float)umv[1];
    float im0 = (float)imv[0], im1 = (float)imv[1];
    float s_mm  = um0 * im0 + um1 * im1;
    float s_upv = um0 * pv.x + um1 * pv.y;
    float s_ipk = im0 * pk.x + im1 * pk.y;
    float s_li  = (float)liv[0] * im0 + (float)liv[1] * im1;
    float s_lu  = (float)luv[0] * im0 + (float)luv[1] * im1;
#pragma unroll
    for (int d = 32; d; d >>= 1) {
        s_mm  += __shfl_xor(s_mm, d);
        s_upv += __shfl_xor(s_upv, d);
        s_ipk += __shfl_xor(s_ipk, d);
        s_li  += __shfl_xor(s_li, d);
        s_lu  += __shfl_xor(s_lu, d);
    }
    if (lane == 0) {
        e_ui[e]  = (s_mm + s_upv) * INV_SQRT_D;
        e_iu[e]  = (s_mm + s_ipk) * INV_SQRT_D;
        a_log[e] = s_li * INV_SQRT_D;
        b_log[e] = s_lu * INV_SQRT_D;
    }
}

// ---------------- per-user softmax + message accumulation (one wave per user) ----------------
__global__ __launch_bounds__(256) void user_messages(const int* __restrict__ u_off, const int* __restrict__ u_list,
                                                     const int* __restrict__ ei, const int* __restrict__ riu,
                                                     const float* __restrict__ e_ui, const float* __restrict__ a_log,
                                                     const __bf16* __restrict__ imb, const __bf16* __restrict__ im,
                                                     const float* __restrict__ pK,
                                                     float* __restrict__ hLu, float* __restrict__ hSu, int nu) {
    int u = blockIdx.x * 4 + (threadIdx.x >> 6);
    if (u >= nu) return;
    int lane = threadIdx.x & 63;
    int off = u_off[u], n = u_off[u + 1] - off;
    float a1x = 0.f, a1y = 0.f, a2x = 0.f, a2y = 0.f;
    if (n > 0) {
        float m1 = -INFINITY, m2 = -INFINITY;
        for (int i = lane; i < n; i += 64) {
            int e = u_list[off + i];
            m1 = fmaxf(m1, e_ui[e]);
            m2 = fmaxf(m2, a_log[e]);
        }
#pragma unroll
        for (int d = 32; d; d >>= 1) {
            m1 = fmaxf(m1, __shfl_xor(m1, d));
            m2 = fmaxf(m2, __shfl_xor(m2, d));
        }
        float s1 = 0.f, s2 = 0.f;
        for (int i = lane; i < n; i += 64) {
            int e = u_list[off + i];
            s1 += expf(e_ui[e] - m1);
            s2 += expf(a_log[e] - m2);
        }
#pragma unroll
        for (int d = 32; d; d >>= 1) {
            s1 += __shfl_xor(s1, d);
            s2 += __shfl_xor(s2, d);
        }
        float inv1 = 1.f / s1, inv2 = 1.f / s2;
        for (int i = 0; i < n; i++) {
            int e = u_list[off + i];
            int item = ei[e];
            float w1 = expf(e_ui[e] - m1) * inv1;
            float w2 = expf(a_log[e] - m2) * inv2;
            bf16x2 vb = ((const bf16x2*)(imb + (size_t)item * D_))[lane];
            bf16x2 vi = ((const bf16x2*)(im + (size_t)item * D_))[lane];
            float2 pk = ((const float2*)(pK + (size_t)riu[e] * D_))[lane];
            a1x += w1 * ((float)vb[0] + pk.x);
            a1y += w1 * ((float)vb[1] + pk.y);
            a2x += w2 * ((float)vi[0] + 1.f);
            a2y += w2 * ((float)vi[1] + 1.f);
        }
    }
    ((float2*)(hLu + (size_t)u * D_))[lane] = make_float2(a1x, a1y);
    ((float2*)(hSu + (size_t)u * D_))[lane] = make_float2(a2x, a2y);
}

// ---------------- per-item softmax + message accumulation (one wave per item) ----------------
__global__ __launch_bounds__(256) void item_messages(const int* __restrict__ i_off, const int* __restrict__ i_list,
                                                     const int* __restrict__ eu, const int* __restrict__ rui,
                                                     const float* __restrict__ e_iu, const float* __restrict__ b_log,
                                                     const __bf16* __restrict__ umb, const __bf16* __restrict__ um,
                                                     const float* __restrict__ pV,
                                                     float* __restrict__ hLi, float* __restrict__ hSi, int ni) {
    int it = blockIdx.x * 4 + (threadIdx.x >> 6);
    if (it >= ni) return;
    int lane = threadIdx.x & 63;
    int off = i_off[it], n = i_off[it + 1] - off;
    float a1x = 0.f, a1y = 0.f, a2x = 0.f, a2y = 0.f;
    if (n > 0) {
        float m1 = -INFINITY, m2 = -INFINITY;
        for (int i = lane; i < n; i += 64) {
            int e = i_list[off + i];
            m1 = fmaxf(m1, e_iu[e]);
            m2 = fmaxf(m2, b_log[e]);
        }
#pragma unroll
        for (int d = 32; d; d >>= 1) {
            m1 = fmaxf(m1, __shfl_xor(m1, d));
            m2 = fmaxf(m2, __shfl_xor(m2, d));
        }
        float s1 = 0.f, s2 = 0.f;
        for (int i = lane; i < n; i += 64) {
            int e = i_list[off + i];
            s1 += expf(e_iu[e] - m1);
            s2 += expf(b_log[e] - m2);
        }
#pragma unroll
        for (int d = 32; d; d >>= 1) {
            s1 += __shfl_xor(s1, d);
            s2 += __shfl_xor(s2, d);
        }
        float inv1 = 1.f / s1, inv2 = 1.f / s2;
        for (int i = 0; i < n; i++) {
            int e = i_list[off + i];
            int user = eu[e];
            float w1 = expf(e_iu[e] - m1) * inv1;
            float w2 = expf(b_log[e] - m2) * inv2;
            bf16x2 vb = ((const bf16x2*)(umb + (size_t)user * D_))[lane];
            bf16x2 vu = ((const bf16x2*)(um + (size_t)user * D_))[lane];
            float2 pv = ((const float2*)(pV + (size_t)rui[e] * D_))[lane];
            a1x += w1 * ((float)vb[0] + pv.x);
            a1y += w1 * ((float)vb[1] + pv.y);
            a2x += w2 * ((float)vu[0] + 1.f);
            a2y += w2 * ((float)vu[1] + 1.f);
        }
    }
    ((float2*)(hLi + (size_t)it * D_))[lane] = make_float2(a1x, a1y);
    ((float2*)(hSi + (size_t)it * D_))[lane] = make_float2(a2x, a2y);
}

extern "C" void kernel_launch(void* const* d_in, const int* in_sizes, int n_in,
                              void* d_out, int out_size, void* d_ws, size_t ws_size,
                              hipStream_t stream) {
    (void)n_in; (void)out_size; (void)ws_size;
    const float* u_emb = (const float*)d_in[0];
    const float* i_emb = (const float*)d_in[1];
    const int* edge_u = (const int*)d_in[2];
    const int* edge_i = (const int*)d_in[3];
    const int* rui = (const int*)d_in[4];
    const int* riu = (const int*)d_in[5];
    const int* last_u_items = (const int*)d_in[6];
    const int* last_i_users = (const int*)d_in[7];
    const float* W1  = (const float*)d_in[8];
    const float* W2  = (const float*)d_in[9];
    const float* W1b = (const float*)d_in[10];
    const float* W2b = (const float*)d_in[11];
    const float* W3  = (const float*)d_in[12];
    const float* W4  = (const float*)d_in[13];
    const float* pV  = (const float*)d_in[14];
    const float* pK  = (const float*)d_in[15];
    const float* last_user_table = (const float*)d_in[16];
    const float* last_item_table = (const float*)d_in[17];

    const int NU = in_sizes[0] / D_;
    const int NI = in_sizes[1] / D_;
    const int E  = in_sizes[2];

    size_t cur = 0;
    auto alloc = [&](size_t bytes) -> void* {
        void* p = (char*)d_ws + cur;
        cur += (bytes + 255) & ~(size_t)255;
        return p;
    };

    __bf16* Wb     = (__bf16*)alloc(6 * 16384 * sizeof(__bf16));
    __bf16* um_bf  = (__bf16*)alloc((size_t)NU * D_ * 2);
    __bf16* umb_bf = (__bf16*)alloc((size_t)NU * D_ * 2);
    __bf16* li_bf  = (__bf16*)alloc((size_t)NU * D_ * 2);
    __bf16* lu_bf  = (__bf16*)alloc((size_t)NU * D_ * 2);
    __bf16* im_bf  = (__bf16*)alloc((size_t)NI * D_ * 2);
    __bf16* imb_bf = (__bf16*)alloc((size_t)NI * D_ * 2);
    float* e_ui  = (float*)alloc((size_t)E * 4);
    float* e_iu  = (float*)alloc((size_t)E * 4);
    float* a_log = (float*)alloc((size_t)E * 4);
    float* b_log = (float*)alloc((size_t)E * 4);
    int* u_cnt  = (int*)alloc((size_t)NU * 4);
    int* u_off  = (int*)alloc((size_t)(NU + 1) * 4);
    int* u_pos  = (int*)alloc((size_t)NU * 4);
    int* u_list = (int*)alloc((size_t)E * 4);
    int* i_cnt  = (int*)alloc((size_t)NI * 4);
    int* i_off  = (int*)alloc((size_t)(NI + 1) * 4);
    int* i_pos  = (int*)alloc((size_t)NI * 4);
    int* i_list = (int*)alloc((size_t)E * 4);

    float* out = (float*)d_out;
    float* hLu = out;
    float* hSu = out + (size_t)NU * D_;
    float* hLi = out + (size_t)2 * NU * D_;
    float* hSi = out + (size_t)2 * NU * D_ + (size_t)NI * D_;

    // weights -> bf16
    W6 w6;
    w6.p[0] = W1; w6.p[1] = W2; w6.p[2] = W1b; w6.p[3] = W2b; w6.p[4] = W3; w6.p[5] = W4;
    cvt_weights<<<(6 * 16384 + 255) / 256, 256, 0, stream>>>(w6, Wb);

    // CSR build
    hipMemsetAsync(u_cnt, 0, (size_t)NU * 4, stream);
    hipMemsetAsync(i_cnt, 0, (size_t)NI * 4, stream);
    hist2<<<(E + 255) / 256, 256, 0, stream>>>(edge_u, edge_i, u_cnt, i_cnt, E);
    scan_pos<<<1, 256, 0, stream>>>(u_cnt, u_off, u_pos, NU);
    scan_pos<<<1, 256, 0, stream>>>(i_cnt, i_off, i_pos, NI);
    scatter2<<<(E + 255) / 256, 256, 0, stream>>>(edge_u, edge_i, u_pos, i_pos, u_list, i_list, E);

    // GEMMs: y = x @ W.T  (messages stored bf16)
    int gu = (NU + 63) / 64, gi = (NI + 63) / 64;
    gemm_xwt<<<gi, 256, 0, stream>>>(i_emb, nullptr, Wb + 0 * 16384, im_bf, NI);   // W1
    gemm_xwt<<<gu, 256, 0, stream>>>(u_emb, nullptr, Wb + 1 * 16384, um_bf, NU);   // W2
    gemm_xwt<<<gi, 256, 0, stream>>>(i_emb, nullptr, Wb + 2 * 16384, imb_bf, NI);  // W1b
    gemm_xwt<<<gu, 256, 0, stream>>>(u_emb, nullptr, Wb + 3 * 16384, umb_bf, NU);  // W2b
    gemm_xwt<<<gu, 256, 0, stream>>>(last_item_table, last_u_items, Wb + 4 * 16384, li_bf, NU); // W3
    gemm_xwt<<<gu, 256, 0, stream>>>(last_user_table, last_i_users, Wb + 5 * 16384, lu_bf, NU); // W4

    // per-edge logits
    edge_dots<<<(E + 3) / 4, 256, 0, stream>>>(um_bf, im_bf, li_bf, lu_bf, pV, pK,
                                               edge_u, edge_i, rui, riu,
                                               e_ui, e_iu, a_log, b_log, E);

    // segment softmax + message passing
    user_messages<<<(NU + 3) / 4, 256, 0, stream>>>(u_off, u_list, edge_i, riu, e_ui, a_log,
                                                    imb_bf, im_bf, pK, hLu, hSu, NU);
    item_messages<<<(NI + 3) / 4, 256, 0, stream>>>(i_off, i_list, edge_u, rui, e_iu, b_log,
                                                    umb_bf, um_bf, pV, hLi, hSi, NI);
}

// Round 2
// 757.994 us; speedup vs baseline: 1.1720x; 1.1720x over previous
//
#include <hip/hip_runtime.h>
#include <hip/hip_bf16.h>
#include <math.h>

#define D_ 128
#define INV_SQRT_D 0.08838834764831845f

typedef __bf16 bf16x8 __attribute__((ext_vector_type(8)));
typedef __bf16 bf16x4 __attribute__((ext_vector_type(4)));
typedef __bf16 bf16x2 __attribute__((ext_vector_type(2)));
typedef float f32x4 __attribute__((ext_vector_type(4)));

struct W6 { const float* p[6]; };

__device__ __forceinline__ void unpack8(bf16x8 v, float* f) {
    const uint32_t* u = (const uint32_t*)&v;
#pragma unroll
    for (int i = 0; i < 4; i++) {
        uint32_t w = u[i];
        f[2 * i]     = __uint_as_float(w << 16);
        f[2 * i + 1] = __uint_as_float(w & 0xffff0000u);
    }
}

__device__ __forceinline__ void unpack4(bf16x4 v, float* f) {
    const uint32_t* u = (const uint32_t*)&v;
#pragma unroll
    for (int i = 0; i < 2; i++) {
        uint32_t w = u[i];
        f[2 * i]     = __uint_as_float(w << 16);
        f[2 * i + 1] = __uint_as_float(w & 0xffff0000u);
    }
}

// ---------------- weight f32 -> bf16 ----------------
__global__ __launch_bounds__(256) void cvt_weights(W6 w, __bf16* __restrict__ out) {
    int idx = blockIdx.x * 256 + threadIdx.x;
    if (idx >= 6 * 16384) return;
    out[idx] = (__bf16)w.p[idx >> 14][idx & 16383];
}

__global__ __launch_bounds__(256) void cvt2(const float* __restrict__ a, const float* __restrict__ b,
                                            __bf16* __restrict__ oa, __bf16* __restrict__ ob, int n) {
    int idx = blockIdx.x * 256 + threadIdx.x;
    if (idx < n) { oa[idx] = (__bf16)a[idx]; ob[idx] = (__bf16)b[idx]; }
}

// ---------------- GEMM: Y = X[gidx] @ W^T (single W) ----------------
__global__ __launch_bounds__(256) void gemm_xwt(const float* __restrict__ X,
                                                const int* __restrict__ gidx,
                                                const __bf16* __restrict__ Wb,
                                                __bf16* __restrict__ Y, int rows) {
    int lane = threadIdx.x & 63;
    int wave = threadIdx.x >> 6;
    int row0 = blockIdx.x * 64 + wave * 16;
    if (row0 >= rows) return;
    int l16 = lane & 15, kh = lane >> 4;
    int ar = row0 + l16;
    int arc = ar < rows ? ar : rows - 1;
    long srcrow = gidx ? (long)gidx[arc] : (long)arc;
    const float* arow = X + (size_t)srcrow * D_;

    f32x4 acc[8] = {};
#pragma unroll
    for (int k0 = 0; k0 < D_; k0 += 32) {
        int kk = k0 + kh * 8;
        float4 a0 = *(const float4*)(arow + kk);
        float4 a1 = *(const float4*)(arow + kk + 4);
        bf16x8 af;
        af[0] = (__bf16)a0.x; af[1] = (__bf16)a0.y; af[2] = (__bf16)a0.z; af[3] = (__bf16)a0.w;
        af[4] = (__bf16)a1.x; af[5] = (__bf16)a1.y; af[6] = (__bf16)a1.z; af[7] = (__bf16)a1.w;
#pragma unroll
        for (int cb = 0; cb < 8; cb++) {
            bf16x8 bf = *(const bf16x8*)(Wb + (size_t)(cb * 16 + l16) * D_ + kk);
            acc[cb] = __builtin_amdgcn_mfma_f32_16x16x32_bf16(af, bf, acc[cb], 0, 0, 0);
        }
    }
#pragma unroll
    for (int cb = 0; cb < 8; cb++) {
#pragma unroll
        for (int j = 0; j < 4; j++) {
            int r = row0 + kh * 4 + j;
            if (r < rows) Y[(size_t)r * D_ + cb * 16 + l16] = (__bf16)acc[cb][j];
        }
    }
}

// ---------------- GEMM dual: YA = X @ WA^T, YB = X @ WB^T (shared X read) ----------------
__global__ __launch_bounds__(256) void gemm_dual(const float* __restrict__ X,
                                                 const __bf16* __restrict__ WA,
                                                 const __bf16* __restrict__ WB,
                                                 __bf16* __restrict__ YA,
                                                 __bf16* __restrict__ YB, int rows) {
    int lane = threadIdx.x & 63;
    int wave = threadIdx.x >> 6;
    int row0 = blockIdx.x * 64 + wave * 16;
    if (row0 >= rows) return;
    int l16 = lane & 15, kh = lane >> 4;
    int ar = row0 + l16;
    int arc = ar < rows ? ar : rows - 1;
    const float* arow = X + (size_t)arc * D_;

    f32x4 accA[8] = {}, accB[8] = {};
#pragma unroll
    for (int k0 = 0; k0 < D_; k0 += 32) {
        int kk = k0 + kh * 8;
        float4 a0 = *(const float4*)(arow + kk);
        float4 a1 = *(const float4*)(arow + kk + 4);
        bf16x8 af;
        af[0] = (__bf16)a0.x; af[1] = (__bf16)a0.y; af[2] = (__bf16)a0.z; af[3] = (__bf16)a0.w;
        af[4] = (__bf16)a1.x; af[5] = (__bf16)a1.y; af[6] = (__bf16)a1.z; af[7] = (__bf16)a1.w;
#pragma unroll
        for (int cb = 0; cb < 8; cb++) {
            bf16x8 bfA = *(const bf16x8*)(WA + (size_t)(cb * 16 + l16) * D_ + kk);
            accA[cb] = __builtin_amdgcn_mfma_f32_16x16x32_bf16(af, bfA, accA[cb], 0, 0, 0);
            bf16x8 bfB = *(const bf16x8*)(WB + (size_t)(cb * 16 + l16) * D_ + kk);
            accB[cb] = __builtin_amdgcn_mfma_f32_16x16x32_bf16(af, bfB, accB[cb], 0, 0, 0);
        }
    }
#pragma unroll
    for (int cb = 0; cb < 8; cb++) {
#pragma unroll
        for (int j = 0; j < 4; j++) {
            int r = row0 + kh * 4 + j;
            if (r < rows) {
                YA[(size_t)r * D_ + cb * 16 + l16] = (__bf16)accA[cb][j];
                YB[(size_t)r * D_ + cb * 16 + l16] = (__bf16)accB[cb][j];
            }
        }
    }
}

// ---------------- small GEMM: Y(rows x ncols, f32) = Xb(bf16) @ P^T (P: ncols x 128 bf16) ----------------
__global__ __launch_bounds__(256) void gemm_pvk(const __bf16* __restrict__ Xb,
                                                const __bf16* __restrict__ Pb,
                                                float* __restrict__ Y, int rows, int ncols) {
    int lane = threadIdx.x & 63;
    int wave = threadIdx.x >> 6;
    int row0 = blockIdx.x * 64 + wave * 16;
    if (row0 >= rows) return;
    int l16 = lane & 15, kh = lane >> 4;
    int ar = row0 + l16;
    int arc = ar < rows ? ar : rows - 1;
    const __bf16* arow = Xb + (size_t)arc * D_;

    f32x4 acc[4] = {};
#pragma unroll
    for (int k0 = 0; k0 < D_; k0 += 32) {
        int kk = k0 + kh * 8;
        bf16x8 af = *(const bf16x8*)(arow + kk);
#pragma unroll
        for (int cb = 0; cb < 4; cb++) {
            int br = cb * 16 + l16;
            if (br >= ncols) br = ncols - 1;
            bf16x8 bf = *(const bf16x8*)(Pb + (size_t)br * D_ + kk);
            acc[cb] = __builtin_amdgcn_mfma_f32_16x16x32_bf16(af, bf, acc[cb], 0, 0, 0);
        }
    }
#pragma unroll
    for (int cb = 0; cb < 4; cb++) {
        int col = cb * 16 + l16;
        if (col >= ncols) continue;
#pragma unroll
        for (int j = 0; j < 4; j++) {
            int r = row0 + kh * 4 + j;
            if (r < rows) Y[(size_t)r * ncols + col] = acc[cb][j];
        }
    }
}

// ---------------- CSR build ----------------
__global__ __launch_bounds__(256) void hist2(const int* __restrict__ eu, const int* __restrict__ ei,
                                             int* __restrict__ ucnt, int* __restrict__ icnt, int E) {
    int e = blockIdx.x * 256 + threadIdx.x;
    if (e < E) {
        atomicAdd(&ucnt[eu[e]], 1);
        atomicAdd(&icnt[ei[e]], 1);
    }
}

// single-block chunked exclusive scan (1024 threads); off[n] = total; pos = copy of off
__global__ __launch_bounds__(1024) void scan_pos(const int* __restrict__ cnt, int* __restrict__ off,
                                                 int* __restrict__ pos, int n) {
    __shared__ int wsum[16];
    __shared__ int run_s;
    int t = threadIdx.x, lane = t & 63, w = t >> 6;
    if (t == 0) run_s = 0;
    __syncthreads();
    const int CH = 16, TILE = 1024 * CH;
    for (int base = 0; base < n; base += TILE) {
        int loc[CH];
        int tot = 0;
        int i0 = base + t * CH;
#pragma unroll
        for (int j = 0; j < CH; j++) {
            int v = (i0 + j < n) ? cnt[i0 + j] : 0;
            loc[j] = tot; tot += v;
        }
        int x = tot;
#pragma unroll
        for (int d = 1; d < 64; d <<= 1) {
            int y = __shfl_up(x, d);
            if (lane >= d) x += y;
        }
        if (lane == 63) wsum[w] = x;
        __syncthreads();
        int wbase = 0;
        for (int ww = 0; ww < w; ww++) wbase += wsum[ww];
        int excl = run_s + wbase + x - tot;
#pragma unroll
        for (int j = 0; j < CH; j++) {
            if (i0 + j < n) { off[i0 + j] = excl + loc[j]; pos[i0 + j] = excl + loc[j]; }
        }
        __syncthreads();
        if (t == 1023) run_s += wbase + x;
        __syncthreads();
    }
    if (t == 0) off[n] = run_s;
}

__global__ __launch_bounds__(256) void scatter2(const int* __restrict__ eu, const int* __restrict__ ei,
                                                int* __restrict__ upos, int* __restrict__ ipos,
                                                int* __restrict__ ulist, int* __restrict__ ilist, int E) {
    int e = blockIdx.x * 256 + threadIdx.x;
    if (e < E) {
        int pu = atomicAdd(&upos[eu[e]], 1);
        ulist[pu] = e;
        int pi = atomicAdd(&ipos[ei[e]], 1);
        ilist[pi] = e;
    }
}

// ---------------- per-edge logits: 16 lanes/edge, 4 edges/wave ----------------
__global__ __launch_bounds__(256) void edge_dots16(const __bf16* __restrict__ um, const __bf16* __restrict__ im,
                                                   const __bf16* __restrict__ li, const __bf16* __restrict__ lu,
                                                   const float* __restrict__ upv, const float* __restrict__ ipk,
                                                   const int* __restrict__ eu, const int* __restrict__ ei,
                                                   const int* __restrict__ rui, const int* __restrict__ riu,
                                                   float* __restrict__ e_ui, float* __restrict__ e_iu,
                                                   float* __restrict__ a_log, float* __restrict__ b_log,
                                                   int E, int umax, int imax) {
    int wave = threadIdx.x >> 6;
    int lane = threadIdx.x & 63;
    int g = lane >> 4, l16 = lane & 15;
    int e = blockIdx.x * 16 + wave * 4 + g;
    if (e >= E) return;
    int u = eu[e], it = ei[e];
    bf16x8 umv = ((const bf16x8*)(um + (size_t)u * D_))[l16];
    bf16x8 imv = ((const bf16x8*)(im + (size_t)it * D_))[l16];
    bf16x8 liv = ((const bf16x8*)(li + (size_t)u * D_))[l16];
    bf16x8 luv = ((const bf16x8*)(lu + (size_t)u * D_))[l16];
    float fu[8], fi[8], fl[8], fg[8];
    unpack8(umv, fu); unpack8(imv, fi); unpack8(liv, fl); unpack8(luv, fg);
    float s_mm = 0.f, s_li = 0.f, s_lu = 0.f;
#pragma unroll
    for (int j = 0; j < 8; j++) {
        s_mm = fmaf(fu[j], fi[j], s_mm);
        s_li = fmaf(fl[j], fi[j], s_li);
        s_lu = fmaf(fg[j], fi[j], s_lu);
    }
#pragma unroll
    for (int d = 1; d < 16; d <<= 1) {
        s_mm += __shfl_xor(s_mm, d);
        s_li += __shfl_xor(s_li, d);
        s_lu += __shfl_xor(s_lu, d);
    }
    if (l16 == 0) {
        float uv = upv[(size_t)u * umax + rui[e]];
        float iv = ipk[(size_t)it * imax + riu[e]];
        e_ui[e]  = (s_mm + uv) * INV_SQRT_D;
        e_iu[e]  = (s_mm + iv) * INV_SQRT_D;
        a_log[e] = s_li * INV_SQRT_D;
        b_log[e] = s_lu * INV_SQRT_D;
    }
}

// ---------------- per-user softmax + messages: 1 user/wave, 2 edges in flight (32-lane groups) ----------------
__global__ __launch_bounds__(256) void user_messages(const int* __restrict__ u_off, const int* __restrict__ u_list,
                                                     const int* __restrict__ ei, const int* __restrict__ riu,
                                                     const float* __restrict__ e_ui, const float* __restrict__ a_log,
                                                     const __bf16* __restrict__ imb, const __bf16* __restrict__ im,
                                                     const __bf16* __restrict__ pKb,
                                                     float* __restrict__ hLu, float* __restrict__ hSu, int nu) {
    int u = blockIdx.x * 4 + (threadIdx.x >> 6);
    if (u >= nu) return;
    int lane = threadIdx.x & 63;
    int g = lane >> 5, l32 = lane & 31;
    int off = u_off[u], n = u_off[u + 1] - off;
    float a1[4] = {}, a2[4] = {};
    float s1 = 0.f, s2 = 0.f;
    float m1 = -INFINITY, m2 = -INFINITY;
    for (int i = lane; i < n; i += 64) {
        int e = u_list[off + i];
        m1 = fmaxf(m1, e_ui[e]);
        m2 = fmaxf(m2, a_log[e]);
    }
#pragma unroll
    for (int d = 32; d; d >>= 1) {
        m1 = fmaxf(m1, __shfl_xor(m1, d));
        m2 = fmaxf(m2, __shfl_xor(m2, d));
    }
    for (int i = g; i < n; i += 2) {
        int e = u_list[off + i];
        float w1 = __expf(e_ui[e] - m1);
        float w2 = __expf(a_log[e] - m2);
        int item = ei[e];
        bf16x4 vb = ((const bf16x4*)(imb + (size_t)item * D_))[l32];
        bf16x4 vi = ((const bf16x4*)(im + (size_t)item * D_))[l32];
        bf16x4 pk = ((const bf16x4*)(pKb + (size_t)riu[e] * D_))[l32];
        float fb[4], fv[4], fp[4];
        unpack4(vb, fb); unpack4(vi, fv); unpack4(pk, fp);
        s1 += w1; s2 += w2;
#pragma unroll
        for (int j = 0; j < 4; j++) {
            a1[j] = fmaf(w1, fb[j] + fp[j], a1[j]);
            a2[j] = fmaf(w2, fv[j] + 1.f, a2[j]);
        }
    }
#pragma unroll
    for (int j = 0; j < 4; j++) {
        a1[j] += __shfl_xor(a1[j], 32);
        a2[j] += __shfl_xor(a2[j], 32);
    }
    s1 += __shfl_xor(s1, 32);
    s2 += __shfl_xor(s2, 32);
    float inv1 = n > 0 ? 1.f / s1 : 0.f;
    float inv2 = n > 0 ? 1.f / s2 : 0.f;
    if (lane < 32) {
        float4 o1 = make_float4(a1[0] * inv1, a1[1] * inv1, a1[2] * inv1, a1[3] * inv1);
        float4 o2 = make_float4(a2[0] * inv2, a2[1] * inv2, a2[2] * inv2, a2[3] * inv2);
        ((float4*)(hLu + (size_t)u * D_))[lane] = o1;
        ((float4*)(hSu + (size_t)u * D_))[lane] = o2;
    }
}

// ---------------- per-item softmax + messages ----------------
__global__ __launch_bounds__(256) void item_messages(const int* __restrict__ i_off, const int* __restrict__ i_list,
                                                     const int* __restrict__ eu, const int* __restrict__ rui,
                                                     const float* __restrict__ e_iu, const float* __restrict__ b_log,
                                                     const __bf16* __restrict__ umb, const __bf16* __restrict__ um,
                                                     const __bf16* __restrict__ pVb,
                                                     float* __restrict__ hLi, float* __restrict__ hSi, int ni) {
    int it = blockIdx.x * 4 + (threadIdx.x >> 6);
    if (it >= ni) return;
    int lane = threadIdx.x & 63;
    int g = lane >> 5, l32 = lane & 31;
    int off = i_off[it], n = i_off[it + 1] - off;
    float a1[4] = {}, a2[4] = {};
    float s1 = 0.f, s2 = 0.f;
    float m1 = -INFINITY, m2 = -INFINITY;
    for (int i = lane; i < n; i += 64) {
        int e = i_list[off + i];
        m1 = fmaxf(m1, e_iu[e]);
        m2 = fmaxf(m2, b_log[e]);
    }
#pragma unroll
    for (int d = 32; d; d >>= 1) {
        m1 = fmaxf(m1, __shfl_xor(m1, d));
        m2 = fmaxf(m2, __shfl_xor(m2, d));
    }
    for (int i = g; i < n; i += 2) {
        int e = i_list[off + i];
        float w1 = __expf(e_iu[e] - m1);
        float w2 = __expf(b_log[e] - m2);
        int user = eu[e];
        bf16x4 vb = ((const bf16x4*)(umb + (size_t)user * D_))[l32];
        bf16x4 vu = ((const bf16x4*)(um + (size_t)user * D_))[l32];
        bf16x4 pv = ((const bf16x4*)(pVb + (size_t)rui[e] * D_))[l32];
        float fb[4], fv[4], fp[4];
        unpack4(vb, fb); unpack4(vu, fv); unpack4(pv, fp);
        s1 += w1; s2 += w2;
#pragma unroll
        for (int j = 0; j < 4; j++) {
            a1[j] = fmaf(w1, fb[j] + fp[j], a1[j]);
            a2[j] = fmaf(w2, fv[j] + 1.f, a2[j]);
        }
    }
#pragma unroll
    for (int j = 0; j < 4; j++) {
        a1[j] += __shfl_xor(a1[j], 32);
        a2[j] += __shfl_xor(a2[j], 32);
    }
    s1 += __shfl_xor(s1, 32);
    s2 += __shfl_xor(s2, 32);
    float inv1 = n > 0 ? 1.f / s1 : 0.f;
    float inv2 = n > 0 ? 1.f / s2 : 0.f;
    if (lane < 32) {
        float4 o1 = make_float4(a1[0] * inv1, a1[1] * inv1, a1[2] * inv1, a1[3] * inv1);
        float4 o2 = make_float4(a2[0] * inv2, a2[1] * inv2, a2[2] * inv2, a2[3] * inv2);
        ((float4*)(hLi + (size_t)it * D_))[lane] = o1;
        ((float4*)(hSi + (size_t)it * D_))[lane] = o2;
    }
}

extern "C" void kernel_launch(void* const* d_in, const int* in_sizes, int n_in,
                              void* d_out, int out_size, void* d_ws, size_t ws_size,
                              hipStream_t stream) {
    (void)n_in; (void)out_size; (void)ws_size;
    const float* u_emb = (const float*)d_in[0];
    const float* i_emb = (const float*)d_in[1];
    const int* edge_u = (const int*)d_in[2];
    const int* edge_i = (const int*)d_in[3];
    const int* rui = (const int*)d_in[4];
    const int* riu = (const int*)d_in[5];
    const int* last_u_items = (const int*)d_in[6];
    const int* last_i_users = (const int*)d_in[7];
    const float* W1  = (const float*)d_in[8];
    const float* W2  = (const float*)d_in[9];
    const float* W1b = (const float*)d_in[10];
    const float* W2b = (const float*)d_in[11];
    const float* W3  = (const float*)d_in[12];
    const float* W4  = (const float*)d_in[13];
    const float* pV  = (const float*)d_in[14];
    const float* pK  = (const float*)d_in[15];
    const float* last_user_table = (const float*)d_in[16];
    const float* last_item_table = (const float*)d_in[17];

    const int NU = in_sizes[0] / D_;
    const int NI = in_sizes[1] / D_;
    const int E  = in_sizes[2];
    const int UMAXr = in_sizes[14] / D_;
    const int IMAXr = in_sizes[15] / D_;

    size_t cur = 0;
    auto alloc = [&](size_t bytes) -> void* {
        void* p = (char*)d_ws + cur;
        cur += (bytes + 255) & ~(size_t)255;
        return p;
    };

    __bf16* Wb     = (__bf16*)alloc(6 * 16384 * sizeof(__bf16));
    __bf16* pVb    = (__bf16*)alloc((size_t)UMAXr * D_ * 2);
    __bf16* pKb    = (__bf16*)alloc((size_t)IMAXr * D_ * 2);
    __bf16* um_bf  = (__bf16*)alloc((size_t)NU * D_ * 2);
    __bf16* umb_bf = (__bf16*)alloc((size_t)NU * D_ * 2);
    __bf16* li_bf  = (__bf16*)alloc((size_t)NU * D_ * 2);
    __bf16* lu_bf  = (__bf16*)alloc((size_t)NU * D_ * 2);
    __bf16* im_bf  = (__bf16*)alloc((size_t)NI * D_ * 2);
    __bf16* imb_bf = (__bf16*)alloc((size_t)NI * D_ * 2);
    float* upv   = (float*)alloc((size_t)NU * UMAXr * 4);
    float* ipk   = (float*)alloc((size_t)NI * IMAXr * 4);
    float* e_ui  = (float*)alloc((size_t)E * 4);
    float* e_iu  = (float*)alloc((size_t)E * 4);
    float* a_log = (float*)alloc((size_t)E * 4);
    float* b_log = (float*)alloc((size_t)E * 4);
    int* u_cnt  = (int*)alloc((size_t)NU * 4);
    int* u_off  = (int*)alloc((size_t)(NU + 1) * 4);
    int* u_pos  = (int*)alloc((size_t)NU * 4);
    int* u_list = (int*)alloc((size_t)E * 4);
    int* i_cnt  = (int*)alloc((size_t)NI * 4);
    int* i_off  = (int*)alloc((size_t)(NI + 1) * 4);
    int* i_pos  = (int*)alloc((size_t)NI * 4);
    int* i_list = (int*)alloc((size_t)E * 4);

    float* out = (float*)d_out;
    float* hLu = out;
    float* hSu = out + (size_t)NU * D_;
    float* hLi = out + (size_t)2 * NU * D_;
    float* hSi = out + (size_t)2 * NU * D_ + (size_t)NI * D_;

    // weights -> bf16
    W6 w6;
    w6.p[0] = W1; w6.p[1] = W2; w6.p[2] = W1b; w6.p[3] = W2b; w6.p[4] = W3; w6.p[5] = W4;
    cvt_weights<<<(6 * 16384 + 255) / 256, 256, 0, stream>>>(w6, Wb);
    cvt2<<<(UMAXr * D_ + 255) / 256, 256, 0, stream>>>(pV, pK, pVb, pKb, UMAXr * D_);

    // CSR build
    hipMemsetAsync(u_cnt, 0, (size_t)NU * 4, stream);
    hipMemsetAsync(i_cnt, 0, (size_t)NI * 4, stream);
    hist2<<<(E + 255) / 256, 256, 0, stream>>>(edge_u, edge_i, u_cnt, i_cnt, E);
    scan_pos<<<1, 1024, 0, stream>>>(u_cnt, u_off, u_pos, NU);
    scan_pos<<<1, 1024, 0, stream>>>(i_cnt, i_off, i_pos, NI);
    scatter2<<<(E + 255) / 256, 256, 0, stream>>>(edge_u, edge_i, u_pos, i_pos, u_list, i_list, E);

    // GEMMs: messages (bf16 outputs), fused per shared input
    int gu = (NU + 63) / 64, gi = (NI + 63) / 64;
    gemm_dual<<<gi, 256, 0, stream>>>(i_emb, Wb + 0 * 16384, Wb + 2 * 16384, im_bf, imb_bf, NI); // W1, W1b
    gemm_dual<<<gu, 256, 0, stream>>>(u_emb, Wb + 1 * 16384, Wb + 3 * 16384, um_bf, umb_bf, NU); // W2, W2b
    gemm_xwt<<<gu, 256, 0, stream>>>(last_item_table, last_u_items, Wb + 4 * 16384, li_bf, NU);  // W3
    gemm_xwt<<<gu, 256, 0, stream>>>(last_user_table, last_i_users, Wb + 5 * 16384, lu_bf, NU);  // W4

    // positional-dot tables: upv[u][r] = um[u]·pV[r], ipk[i][r] = im[i]·pK[r]
    gemm_pvk<<<gu, 256, 0, stream>>>(um_bf, pVb, upv, NU, UMAXr);
    gemm_pvk<<<gi, 256, 0, stream>>>(im_bf, pKb, ipk, NI, IMAXr);

    // per-edge logits
    edge_dots16<<<(E + 15) / 16, 256, 0, stream>>>(um_bf, im_bf, li_bf, lu_bf, upv, ipk,
                                                   edge_u, edge_i, rui, riu,
                                                   e_ui, e_iu, a_log, b_log, E, UMAXr, IMAXr);

    // segment softmax + message passing
    user_messages<<<(NU + 3) / 4, 256, 0, stream>>>(u_off, u_list, edge_i, riu, e_ui, a_log,
                                                    imb_bf, im_bf, pKb, hLu, hSu, NU);
    item_messages<<<(NI + 3) / 4, 256, 0, stream>>>(i_off, i_list, edge_u, rui, e_iu, b_log,
                                                    umb_bf, um_bf, pVb, hLi, hSi, NI);
}

// Round 3
// 576.935 us; speedup vs baseline: 1.5398x; 1.3138x over previous
//
#include <hip/hip_runtime.h>
#include <hip/hip_bf16.h>
#include <math.h>

#define D_ 128
#define INV_SQRT_D 0.08838834764831845f
#define SCAN_CH 16
#define SCAN_TILE (256 * SCAN_CH)   // 4096 elements per block

typedef __bf16 bf16x8 __attribute__((ext_vector_type(8)));
typedef __bf16 bf16x4 __attribute__((ext_vector_type(4)));
typedef float f32x4 __attribute__((ext_vector_type(4)));

struct W6 { const float* p[6]; };

__device__ __forceinline__ void unpack8(bf16x8 v, float* f) {
    const uint32_t* u = (const uint32_t*)&v;
#pragma unroll
    for (int i = 0; i < 4; i++) {
        uint32_t w = u[i];
        f[2 * i]     = __uint_as_float(w << 16);
        f[2 * i + 1] = __uint_as_float(w & 0xffff0000u);
    }
}

__device__ __forceinline__ void unpack4(bf16x4 v, float* f) {
    const uint32_t* u = (const uint32_t*)&v;
#pragma unroll
    for (int i = 0; i < 2; i++) {
        uint32_t w = u[i];
        f[2 * i]     = __uint_as_float(w << 16);
        f[2 * i + 1] = __uint_as_float(w & 0xffff0000u);
    }
}

// ---------------- weight f32 -> bf16 ----------------
__global__ __launch_bounds__(256) void cvt_weights(W6 w, __bf16* __restrict__ out) {
    int idx = blockIdx.x * 256 + threadIdx.x;
    if (idx >= 6 * 16384) return;
    out[idx] = (__bf16)w.p[idx >> 14][idx & 16383];
}

__global__ __launch_bounds__(256) void cvt2(const float* __restrict__ a, const float* __restrict__ b,
                                            __bf16* __restrict__ oa, __bf16* __restrict__ ob, int n) {
    int idx = blockIdx.x * 256 + threadIdx.x;
    if (idx < n) { oa[idx] = (__bf16)a[idx]; ob[idx] = (__bf16)b[idx]; }
}

// ---------------- GEMM: Y = X[gidx] @ W^T (single W) ----------------
__global__ __launch_bounds__(256) void gemm_xwt(const float* __restrict__ X,
                                                const int* __restrict__ gidx,
                                                const __bf16* __restrict__ Wb,
                                                __bf16* __restrict__ Y, int rows) {
    int lane = threadIdx.x & 63;
    int wave = threadIdx.x >> 6;
    int row0 = blockIdx.x * 64 + wave * 16;
    if (row0 >= rows) return;
    int l16 = lane & 15, kh = lane >> 4;
    int ar = row0 + l16;
    int arc = ar < rows ? ar : rows - 1;
    long srcrow = gidx ? (long)gidx[arc] : (long)arc;
    const float* arow = X + (size_t)srcrow * D_;

    f32x4 acc[8] = {};
#pragma unroll
    for (int k0 = 0; k0 < D_; k0 += 32) {
        int kk = k0 + kh * 8;
        float4 a0 = *(const float4*)(arow + kk);
        float4 a1 = *(const float4*)(arow + kk + 4);
        bf16x8 af;
        af[0] = (__bf16)a0.x; af[1] = (__bf16)a0.y; af[2] = (__bf16)a0.z; af[3] = (__bf16)a0.w;
        af[4] = (__bf16)a1.x; af[5] = (__bf16)a1.y; af[6] = (__bf16)a1.z; af[7] = (__bf16)a1.w;
#pragma unroll
        for (int cb = 0; cb < 8; cb++) {
            bf16x8 bf = *(const bf16x8*)(Wb + (size_t)(cb * 16 + l16) * D_ + kk);
            acc[cb] = __builtin_amdgcn_mfma_f32_16x16x32_bf16(af, bf, acc[cb], 0, 0, 0);
        }
    }
#pragma unroll
    for (int cb = 0; cb < 8; cb++) {
#pragma unroll
        for (int j = 0; j < 4; j++) {
            int r = row0 + kh * 4 + j;
            if (r < rows) Y[(size_t)r * D_ + cb * 16 + l16] = (__bf16)acc[cb][j];
        }
    }
}

// ---------------- GEMM dual: YA = X @ WA^T, YB = X @ WB^T (shared X read) ----------------
__global__ __launch_bounds__(256) void gemm_dual(const float* __restrict__ X,
                                                 const __bf16* __restrict__ WA,
                                                 const __bf16* __restrict__ WB,
                                                 __bf16* __restrict__ YA,
                                                 __bf16* __restrict__ YB, int rows) {
    int lane = threadIdx.x & 63;
    int wave = threadIdx.x >> 6;
    int row0 = blockIdx.x * 64 + wave * 16;
    if (row0 >= rows) return;
    int l16 = lane & 15, kh = lane >> 4;
    int ar = row0 + l16;
    int arc = ar < rows ? ar : rows - 1;
    const float* arow = X + (size_t)arc * D_;

    f32x4 accA[8] = {}, accB[8] = {};
#pragma unroll
    for (int k0 = 0; k0 < D_; k0 += 32) {
        int kk = k0 + kh * 8;
        float4 a0 = *(const float4*)(arow + kk);
        float4 a1 = *(const float4*)(arow + kk + 4);
        bf16x8 af;
        af[0] = (__bf16)a0.x; af[1] = (__bf16)a0.y; af[2] = (__bf16)a0.z; af[3] = (__bf16)a0.w;
        af[4] = (__bf16)a1.x; af[5] = (__bf16)a1.y; af[6] = (__bf16)a1.z; af[7] = (__bf16)a1.w;
#pragma unroll
        for (int cb = 0; cb < 8; cb++) {
            bf16x8 bfA = *(const bf16x8*)(WA + (size_t)(cb * 16 + l16) * D_ + kk);
            accA[cb] = __builtin_amdgcn_mfma_f32_16x16x32_bf16(af, bfA, accA[cb], 0, 0, 0);
            bf16x8 bfB = *(const bf16x8*)(WB + (size_t)(cb * 16 + l16) * D_ + kk);
            accB[cb] = __builtin_amdgcn_mfma_f32_16x16x32_bf16(af, bfB, accB[cb], 0, 0, 0);
        }
    }
#pragma unroll
    for (int cb = 0; cb < 8; cb++) {
#pragma unroll
        for (int j = 0; j < 4; j++) {
            int r = row0 + kh * 4 + j;
            if (r < rows) {
                YA[(size_t)r * D_ + cb * 16 + l16] = (__bf16)accA[cb][j];
                YB[(size_t)r * D_ + cb * 16 + l16] = (__bf16)accB[cb][j];
            }
        }
    }
}

// ---------------- small GEMM: Y(rows x ncols, f32) = Xb(bf16) @ P^T ----------------
__global__ __launch_bounds__(256) void gemm_pvk(const __bf16* __restrict__ Xb,
                                                const __bf16* __restrict__ Pb,
                                                float* __restrict__ Y, int rows, int ncols) {
    int lane = threadIdx.x & 63;
    int wave = threadIdx.x >> 6;
    int row0 = blockIdx.x * 64 + wave * 16;
    if (row0 >= rows) return;
    int l16 = lane & 15, kh = lane >> 4;
    int ar = row0 + l16;
    int arc = ar < rows ? ar : rows - 1;
    const __bf16* arow = Xb + (size_t)arc * D_;

    f32x4 acc[4] = {};
#pragma unroll
    for (int k0 = 0; k0 < D_; k0 += 32) {
        int kk = k0 + kh * 8;
        bf16x8 af = *(const bf16x8*)(arow + kk);
#pragma unroll
        for (int cb = 0; cb < 4; cb++) {
            int br = cb * 16 + l16;
            if (br >= ncols) br = ncols - 1;
            bf16x8 bf = *(const bf16x8*)(Pb + (size_t)br * D_ + kk);
            acc[cb] = __builtin_amdgcn_mfma_f32_16x16x32_bf16(af, bf, acc[cb], 0, 0, 0);
        }
    }
#pragma unroll
    for (int cb = 0; cb < 4; cb++) {
        int col = cb * 16 + l16;
        if (col >= ncols) continue;
#pragma unroll
        for (int j = 0; j < 4; j++) {
            int r = row0 + kh * 4 + j;
            if (r < rows) Y[(size_t)r * ncols + col] = acc[cb][j];
        }
    }
}

// ---------------- CSR build (combined users+items) ----------------
__global__ __launch_bounds__(256) void hist2(const int* __restrict__ eu, const int* __restrict__ ei,
                                             int* __restrict__ cnt_all, int nu, int E) {
    int e = blockIdx.x * 256 + threadIdx.x;
    if (e < E) {
        atomicAdd(&cnt_all[eu[e]], 1);
        atomicAdd(&cnt_all[nu + ei[e]], 1);
    }
}

// ---------------- 3-phase multi-block exclusive scan ----------------
__global__ __launch_bounds__(256) void scan_phaseA(const int* __restrict__ cnt, int* __restrict__ part, int n) {
    __shared__ int wsum[4];
    int t = threadIdx.x, lane = t & 63, w = t >> 6;
    int i0 = blockIdx.x * SCAN_TILE + t * SCAN_CH;
    int tot = 0;
#pragma unroll
    for (int j = 0; j < SCAN_CH; j++) tot += (i0 + j < n) ? cnt[i0 + j] : 0;
#pragma unroll
    for (int d = 32; d; d >>= 1) tot += __shfl_xor(tot, d);
    if (lane == 0) wsum[w] = tot;
    __syncthreads();
    if (t == 0) part[blockIdx.x] = wsum[0] + wsum[1] + wsum[2] + wsum[3];
}

// single block (<=1024 partials): exclusive scan of partials; writes off[n]=total
__global__ __launch_bounds__(1024) void scan_phaseB(int* __restrict__ part, int nb,
                                                    int* __restrict__ off, int n) {
    __shared__ int wsum[16];
    int t = threadIdx.x, lane = t & 63, w = t >> 6;
    int v = (t < nb) ? part[t] : 0;
    int x = v;
#pragma unroll
    for (int d = 1; d < 64; d <<= 1) {
        int y = __shfl_up(x, d);
        if (lane >= d) x += y;
    }
    if (lane == 63) wsum[w] = x;
    __syncthreads();
    int wbase = 0;
    for (int ww = 0; ww < w; ww++) wbase += wsum[ww];
    if (t < nb) part[t] = wbase + x - v;
    if (t == 1023) off[n] = wbase + x;  // grand total (2E)
}

__global__ __launch_bounds__(256) void scan_phaseC(const int* __restrict__ cnt, const int* __restrict__ part,
                                                   int* __restrict__ off, int* __restrict__ pos, int n) {
    __shared__ int wsum[4];
    int t = threadIdx.x, lane = t & 63, w = t >> 6;
    int i0 = blockIdx.x * SCAN_TILE + t * SCAN_CH;
    int loc[SCAN_CH];
    int tot = 0;
#pragma unroll
    for (int j = 0; j < SCAN_CH; j++) {
        int v = (i0 + j < n) ? cnt[i0 + j] : 0;
        loc[j] = tot; tot += v;
    }
    int x = tot;
#pragma unroll
    for (int d = 1; d < 64; d <<= 1) {
        int y = __shfl_up(x, d);
        if (lane >= d) x += y;
    }
    if (lane == 63) wsum[w] = x;
    __syncthreads();
    int wbase = 0;
    for (int ww = 0; ww < w; ww++) wbase += wsum[ww];
    int excl = part[blockIdx.x] + wbase + x - tot;
#pragma unroll
    for (int j = 0; j < SCAN_CH; j++) {
        if (i0 + j < n) { off[i0 + j] = excl + loc[j]; pos[i0 + j] = excl + loc[j]; }
    }
}

__global__ __launch_bounds__(256) void scatter2(const int* __restrict__ eu, const int* __restrict__ ei,
                                                int* __restrict__ pos_all, int* __restrict__ list_all,
                                                int nu, int E) {
    int e = blockIdx.x * 256 + threadIdx.x;
    if (e < E) {
        int pu = atomicAdd(&pos_all[eu[e]], 1);
        list_all[pu] = e;
        int pi = atomicAdd(&pos_all[nu + ei[e]], 1);
        list_all[pi] = e;
    }
}

// ---------------- per-edge logits: 16 lanes/edge, 4 edges/wave ----------------
__global__ __launch_bounds__(256) void edge_dots16(const __bf16* __restrict__ um, const __bf16* __restrict__ im,
                                                   const __bf16* __restrict__ li, const __bf16* __restrict__ lu,
                                                   const float* __restrict__ upv, const float* __restrict__ ipk,
                                                   const int* __restrict__ eu, const int* __restrict__ ei,
                                                   const int* __restrict__ rui, const int* __restrict__ riu,
                                                   float* __restrict__ e_ui, float* __restrict__ e_iu,
                                                   float* __restrict__ a_log, float* __restrict__ b_log,
                                                   int E, int umax, int imax) {
    int wave = threadIdx.x >> 6;
    int lane = threadIdx.x & 63;
    int g = lane >> 4, l16 = lane & 15;
    int e = blockIdx.x * 16 + wave * 4 + g;
    if (e >= E) return;
    int u = eu[e], it = ei[e];
    bf16x8 umv = ((const bf16x8*)(um + (size_t)u * D_))[l16];
    bf16x8 imv = ((const bf16x8*)(im + (size_t)it * D_))[l16];
    bf16x8 liv = ((const bf16x8*)(li + (size_t)u * D_))[l16];
    bf16x8 luv = ((const bf16x8*)(lu + (size_t)u * D_))[l16];
    float fu[8], fi[8], fl[8], fg[8];
    unpack8(umv, fu); unpack8(imv, fi); unpack8(liv, fl); unpack8(luv, fg);
    float s_mm = 0.f, s_li = 0.f, s_lu = 0.f;
#pragma unroll
    for (int j = 0; j < 8; j++) {
        s_mm = fmaf(fu[j], fi[j], s_mm);
        s_li = fmaf(fl[j], fi[j], s_li);
        s_lu = fmaf(fg[j], fi[j], s_lu);
    }
#pragma unroll
    for (int d = 1; d < 16; d <<= 1) {
        s_mm += __shfl_xor(s_mm, d);
        s_li += __shfl_xor(s_li, d);
        s_lu += __shfl_xor(s_lu, d);
    }
    if (l16 == 0) {
        float uv = upv[(size_t)u * umax + rui[e]];
        float iv = ipk[(size_t)it * imax + riu[e]];
        e_ui[e]  = (s_mm + uv) * INV_SQRT_D;
        e_iu[e]  = (s_mm + iv) * INV_SQRT_D;
        a_log[e] = s_li * INV_SQRT_D;
        b_log[e] = s_lu * INV_SQRT_D;
    }
}

// ---------------- per-user softmax + messages ----------------
__global__ __launch_bounds__(256) void user_messages(const int* __restrict__ off_all, const int* __restrict__ list_all,
                                                     const int* __restrict__ ei, const int* __restrict__ riu,
                                                     const float* __restrict__ e_ui, const float* __restrict__ a_log,
                                                     const __bf16* __restrict__ imb, const __bf16* __restrict__ im,
                                                     const __bf16* __restrict__ pKb,
                                                     float* __restrict__ hLu, float* __restrict__ hSu, int nu) {
    int u = blockIdx.x * 4 + (threadIdx.x >> 6);
    if (u >= nu) return;
    int lane = threadIdx.x & 63;
    int g = lane >> 5, l32 = lane & 31;
    int off = off_all[u], n = off_all[u + 1] - off;
    float a1[4] = {}, a2[4] = {};
    float s1 = 0.f, s2 = 0.f;
    float m1 = -INFINITY, m2 = -INFINITY;
    for (int i = lane; i < n; i += 64) {
        int e = list_all[off + i];
        m1 = fmaxf(m1, e_ui[e]);
        m2 = fmaxf(m2, a_log[e]);
    }
#pragma unroll
    for (int d = 32; d; d >>= 1) {
        m1 = fmaxf(m1, __shfl_xor(m1, d));
        m2 = fmaxf(m2, __shfl_xor(m2, d));
    }
    for (int i = g; i < n; i += 2) {
        int e = list_all[off + i];
        float w1 = __expf(e_ui[e] - m1);
        float w2 = __expf(a_log[e] - m2);
        int item = ei[e];
        bf16x4 vb = ((const bf16x4*)(imb + (size_t)item * D_))[l32];
        bf16x4 vi = ((const bf16x4*)(im + (size_t)item * D_))[l32];
        bf16x4 pk = ((const bf16x4*)(pKb + (size_t)riu[e] * D_))[l32];
        float fb[4], fv[4], fp[4];
        unpack4(vb, fb); unpack4(vi, fv); unpack4(pk, fp);
        s1 += w1; s2 += w2;
#pragma unroll
        for (int j = 0; j < 4; j++) {
            a1[j] = fmaf(w1, fb[j] + fp[j], a1[j]);
            a2[j] = fmaf(w2, fv[j] + 1.f, a2[j]);
        }
    }
#pragma unroll
    for (int j = 0; j < 4; j++) {
        a1[j] += __shfl_xor(a1[j], 32);
        a2[j] += __shfl_xor(a2[j], 32);
    }
    s1 += __shfl_xor(s1, 32);
    s2 += __shfl_xor(s2, 32);
    float inv1 = n > 0 ? 1.f / s1 : 0.f;
    float inv2 = n > 0 ? 1.f / s2 : 0.f;
    if (lane < 32) {
        float4 o1 = make_float4(a1[0] * inv1, a1[1] * inv1, a1[2] * inv1, a1[3] * inv1);
        float4 o2 = make_float4(a2[0] * inv2, a2[1] * inv2, a2[2] * inv2, a2[3] * inv2);
        ((float4*)(hLu + (size_t)u * D_))[lane] = o1;
        ((float4*)(hSu + (size_t)u * D_))[lane] = o2;
    }
}

// ---------------- per-item softmax + messages ----------------
__global__ __launch_bounds__(256) void item_messages(const int* __restrict__ off_all, const int* __restrict__ list_all,
                                                     const int* __restrict__ eu, const int* __restrict__ rui,
                                                     const float* __restrict__ e_iu, const float* __restrict__ b_log,
                                                     const __bf16* __restrict__ umb, const __bf16* __restrict__ um,
                                                     const __bf16* __restrict__ pVb,
                                                     float* __restrict__ hLi, float* __restrict__ hSi,
                                                     int nu, int ni) {
    int it = blockIdx.x * 4 + (threadIdx.x >> 6);
    if (it >= ni) return;
    int lane = threadIdx.x & 63;
    int g = lane >> 5, l32 = lane & 31;
    int off = off_all[nu + it], n = off_all[nu + it + 1] - off;
    float a1[4] = {}, a2[4] = {};
    float s1 = 0.f, s2 = 0.f;
    float m1 = -INFINITY, m2 = -INFINITY;
    for (int i = lane; i < n; i += 64) {
        int e = list_all[off + i];
        m1 = fmaxf(m1, e_iu[e]);
        m2 = fmaxf(m2, b_log[e]);
    }
#pragma unroll
    for (int d = 32; d; d >>= 1) {
        m1 = fmaxf(m1, __shfl_xor(m1, d));
        m2 = fmaxf(m2, __shfl_xor(m2, d));
    }
    for (int i = g; i < n; i += 2) {
        int e = list_all[off + i];
        float w1 = __expf(e_iu[e] - m1);
        float w2 = __expf(b_log[e] - m2);
        int user = eu[e];
        bf16x4 vb = ((const bf16x4*)(umb + (size_t)user * D_))[l32];
        bf16x4 vu = ((const bf16x4*)(um + (size_t)user * D_))[l32];
        bf16x4 pv = ((const bf16x4*)(pVb + (size_t)rui[e] * D_))[l32];
        float fb[4], fv[4], fp[4];
        unpack4(vb, fb); unpack4(vu, fv); unpack4(pv, fp);
        s1 += w1; s2 += w2;
#pragma unroll
        for (int j = 0; j < 4; j++) {
            a1[j] = fmaf(w1, fb[j] + fp[j], a1[j]);
            a2[j] = fmaf(w2, fv[j] + 1.f, a2[j]);
        }
    }
#pragma unroll
    for (int j = 0; j < 4; j++) {
        a1[j] += __shfl_xor(a1[j], 32);
        a2[j] += __shfl_xor(a2[j], 32);
    }
    s1 += __shfl_xor(s1, 32);
    s2 += __shfl_xor(s2, 32);
    float inv1 = n > 0 ? 1.f / s1 : 0.f;
    float inv2 = n > 0 ? 1.f / s2 : 0.f;
    if (lane < 32) {
        float4 o1 = make_float4(a1[0] * inv1, a1[1] * inv1, a1[2] * inv1, a1[3] * inv1);
        float4 o2 = make_float4(a2[0] * inv2, a2[1] * inv2, a2[2] * inv2, a2[3] * inv2);
        ((float4*)(hLi + (size_t)it * D_))[lane] = o1;
        ((float4*)(hSi + (size_t)it * D_))[lane] = o2;
    }
}

extern "C" void kernel_launch(void* const* d_in, const int* in_sizes, int n_in,
                              void* d_out, int out_size, void* d_ws, size_t ws_size,
                              hipStream_t stream) {
    (void)n_in; (void)out_size; (void)ws_size;
    const float* u_emb = (const float*)d_in[0];
    const float* i_emb = (const float*)d_in[1];
    const int* edge_u = (const int*)d_in[2];
    const int* edge_i = (const int*)d_in[3];
    const int* rui = (const int*)d_in[4];
    const int* riu = (const int*)d_in[5];
    const int* last_u_items = (const int*)d_in[6];
    const int* last_i_users = (const int*)d_in[7];
    const float* W1  = (const float*)d_in[8];
    const float* W2  = (const float*)d_in[9];
    const float* W1b = (const float*)d_in[10];
    const float* W2b = (const float*)d_in[11];
    const float* W3  = (const float*)d_in[12];
    const float* W4  = (const float*)d_in[13];
    const float* pV  = (const float*)d_in[14];
    const float* pK  = (const float*)d_in[15];
    const float* last_user_table = (const float*)d_in[16];
    const float* last_item_table = (const float*)d_in[17];

    const int NU = in_sizes[0] / D_;
    const int NI = in_sizes[1] / D_;
    const int E  = in_sizes[2];
    const int UMAXr = in_sizes[14] / D_;
    const int IMAXr = in_sizes[15] / D_;
    const int NSEG = NU + NI;

    size_t cur = 0;
    auto alloc = [&](size_t bytes) -> void* {
        void* p = (char*)d_ws + cur;
        cur += (bytes + 255) & ~(size_t)255;
        return p;
    };

    __bf16* Wb     = (__bf16*)alloc(6 * 16384 * sizeof(__bf16));
    __bf16* pVb    = (__bf16*)alloc((size_t)UMAXr * D_ * 2);
    __bf16* pKb    = (__bf16*)alloc((size_t)IMAXr * D_ * 2);
    __bf16* um_bf  = (__bf16*)alloc((size_t)NU * D_ * 2);
    __bf16* umb_bf = (__bf16*)alloc((size_t)NU * D_ * 2);
    __bf16* li_bf  = (__bf16*)alloc((size_t)NU * D_ * 2);
    __bf16* lu_bf  = (__bf16*)alloc((size_t)NU * D_ * 2);
    __bf16* im_bf  = (__bf16*)alloc((size_t)NI * D_ * 2);
    __bf16* imb_bf = (__bf16*)alloc((size_t)NI * D_ * 2);
    float* upv   = (float*)alloc((size_t)NU * UMAXr * 4);
    float* ipk   = (float*)alloc((size_t)NI * IMAXr * 4);
    float* e_ui  = (float*)alloc((size_t)E * 4);
    float* e_iu  = (float*)alloc((size_t)E * 4);
    float* a_log = (float*)alloc((size_t)E * 4);
    float* b_log = (float*)alloc((size_t)E * 4);
    int* cnt_all  = (int*)alloc((size_t)NSEG * 4);
    int* off_all  = (int*)alloc((size_t)(NSEG + 1) * 4);
    int* pos_all  = (int*)alloc((size_t)NSEG * 4);
    int* list_all = (int*)alloc((size_t)2 * E * 4);
    int* parts    = (int*)alloc(1024 * 4);

    float* out = (float*)d_out;
    float* hLu = out;
    float* hSu = out + (size_t)NU * D_;
    float* hLi = out + (size_t)2 * NU * D_;
    float* hSi = out + (size_t)2 * NU * D_ + (size_t)NI * D_;

    // weights -> bf16
    W6 w6;
    w6.p[0] = W1; w6.p[1] = W2; w6.p[2] = W1b; w6.p[3] = W2b; w6.p[4] = W3; w6.p[5] = W4;
    cvt_weights<<<(6 * 16384 + 255) / 256, 256, 0, stream>>>(w6, Wb);
    cvt2<<<(UMAXr * D_ + 255) / 256, 256, 0, stream>>>(pV, pK, pVb, pKb, UMAXr * D_);

    // CSR build (combined users+items, multi-block scan)
    hipMemsetAsync(cnt_all, 0, (size_t)NSEG * 4, stream);
    hist2<<<(E + 255) / 256, 256, 0, stream>>>(edge_u, edge_i, cnt_all, NU, E);
    int nb = (NSEG + SCAN_TILE - 1) / SCAN_TILE;
    scan_phaseA<<<nb, 256, 0, stream>>>(cnt_all, parts, NSEG);
    scan_phaseB<<<1, 1024, 0, stream>>>(parts, nb, off_all, NSEG);
    scan_phaseC<<<nb, 256, 0, stream>>>(cnt_all, parts, off_all, pos_all, NSEG);
    scatter2<<<(E + 255) / 256, 256, 0, stream>>>(edge_u, edge_i, pos_all, list_all, NU, E);

    // GEMMs: messages (bf16 outputs), fused per shared input
    int gu = (NU + 63) / 64, gi = (NI + 63) / 64;
    gemm_dual<<<gi, 256, 0, stream>>>(i_emb, Wb + 0 * 16384, Wb + 2 * 16384, im_bf, imb_bf, NI); // W1, W1b
    gemm_dual<<<gu, 256, 0, stream>>>(u_emb, Wb + 1 * 16384, Wb + 3 * 16384, um_bf, umb_bf, NU); // W2, W2b
    gemm_xwt<<<gu, 256, 0, stream>>>(last_item_table, last_u_items, Wb + 4 * 16384, li_bf, NU);  // W3
    gemm_xwt<<<gu, 256, 0, stream>>>(last_user_table, last_i_users, Wb + 5 * 16384, lu_bf, NU);  // W4

    // positional-dot tables
    gemm_pvk<<<gu, 256, 0, stream>>>(um_bf, pVb, upv, NU, UMAXr);
    gemm_pvk<<<gi, 256, 0, stream>>>(im_bf, pKb, ipk, NI, IMAXr);

    // per-edge logits
    edge_dots16<<<(E + 15) / 16, 256, 0, stream>>>(um_bf, im_bf, li_bf, lu_bf, upv, ipk,
                                                   edge_u, edge_i, rui, riu,
                                                   e_ui, e_iu, a_log, b_log, E, UMAXr, IMAXr);

    // segment softmax + message passing
    user_messages<<<(NU + 3) / 4, 256, 0, stream>>>(off_all, list_all, edge_i, riu, e_ui, a_log,
                                                    imb_bf, im_bf, pKb, hLu, hSu, NU);
    item_messages<<<(NI + 3) / 4, 256, 0, stream>>>(off_all, list_all, edge_u, rui, e_iu, b_log,
                                                    umb_bf, um_bf, pVb, hLi, hSi, NU, NI);
}

// Round 4
// 497.709 us; speedup vs baseline: 1.7849x; 1.1592x over previous
//
#include <hip/hip_runtime.h>
#include <hip/hip_bf16.h>
#include <math.h>

#define D_ 128
#define INV_SQRT_D 0.08838834764831845f
#define SCAN_CH 16
#define SCAN_TILE (256 * SCAN_CH)   // 4096 elements per block

typedef __bf16 bf16x8 __attribute__((ext_vector_type(8)));
typedef __bf16 bf16x4 __attribute__((ext_vector_type(4)));
typedef float f32x4 __attribute__((ext_vector_type(4)));

struct W6 { const float* p[6]; };

__device__ __forceinline__ void unpack4(bf16x4 v, float* f) {
    const uint32_t* u = (const uint32_t*)&v;
#pragma unroll
    for (int i = 0; i < 2; i++) {
        uint32_t w = u[i];
        f[2 * i]     = __uint_as_float(w << 16);
        f[2 * i + 1] = __uint_as_float(w & 0xffff0000u);
    }
}

// ---------------- weight f32 -> bf16 ----------------
__global__ __launch_bounds__(256) void cvt_weights(W6 w, __bf16* __restrict__ out) {
    int idx = blockIdx.x * 256 + threadIdx.x;
    if (idx >= 6 * 16384) return;
    out[idx] = (__bf16)w.p[idx >> 14][idx & 16383];
}

__global__ __launch_bounds__(256) void cvt2(const float* __restrict__ a, const float* __restrict__ b,
                                            __bf16* __restrict__ oa, __bf16* __restrict__ ob, int n) {
    int idx = blockIdx.x * 256 + threadIdx.x;
    if (idx < n) { oa[idx] = (__bf16)a[idx]; ob[idx] = (__bf16)b[idx]; }
}

// ---------------- GEMM: Y = X[gidx] @ W^T, strided output ----------------
__global__ __launch_bounds__(256) void gemm_xwt(const float* __restrict__ X,
                                                const int* __restrict__ gidx,
                                                const __bf16* __restrict__ Wb,
                                                __bf16* __restrict__ Y, int ystride, int rows) {
    int lane = threadIdx.x & 63;
    int wave = threadIdx.x >> 6;
    int row0 = blockIdx.x * 64 + wave * 16;
    if (row0 >= rows) return;
    int l16 = lane & 15, kh = lane >> 4;
    int ar = row0 + l16;
    int arc = ar < rows ? ar : rows - 1;
    long srcrow = gidx ? (long)gidx[arc] : (long)arc;
    const float* arow = X + (size_t)srcrow * D_;

    f32x4 acc[8] = {};
#pragma unroll
    for (int k0 = 0; k0 < D_; k0 += 32) {
        int kk = k0 + kh * 8;
        float4 a0 = *(const float4*)(arow + kk);
        float4 a1 = *(const float4*)(arow + kk + 4);
        bf16x8 af;
        af[0] = (__bf16)a0.x; af[1] = (__bf16)a0.y; af[2] = (__bf16)a0.z; af[3] = (__bf16)a0.w;
        af[4] = (__bf16)a1.x; af[5] = (__bf16)a1.y; af[6] = (__bf16)a1.z; af[7] = (__bf16)a1.w;
#pragma unroll
        for (int cb = 0; cb < 8; cb++) {
            bf16x8 bf = *(const bf16x8*)(Wb + (size_t)(cb * 16 + l16) * D_ + kk);
            acc[cb] = __builtin_amdgcn_mfma_f32_16x16x32_bf16(af, bf, acc[cb], 0, 0, 0);
        }
    }
#pragma unroll
    for (int cb = 0; cb < 8; cb++) {
#pragma unroll
        for (int j = 0; j < 4; j++) {
            int r = row0 + kh * 4 + j;
            if (r < rows) Y[(size_t)r * ystride + cb * 16 + l16] = (__bf16)acc[cb][j];
        }
    }
}

// ---------------- GEMM dual: YA = X @ WA^T, YB = X @ WB^T (shared X read), strided ----------------
__global__ __launch_bounds__(256) void gemm_dual(const float* __restrict__ X,
                                                 const __bf16* __restrict__ WA,
                                                 const __bf16* __restrict__ WB,
                                                 __bf16* __restrict__ YA, int sA,
                                                 __bf16* __restrict__ YB, int sB, int rows) {
    int lane = threadIdx.x & 63;
    int wave = threadIdx.x >> 6;
    int row0 = blockIdx.x * 64 + wave * 16;
    if (row0 >= rows) return;
    int l16 = lane & 15, kh = lane >> 4;
    int ar = row0 + l16;
    int arc = ar < rows ? ar : rows - 1;
    const float* arow = X + (size_t)arc * D_;

    f32x4 accA[8] = {}, accB[8] = {};
#pragma unroll
    for (int k0 = 0; k0 < D_; k0 += 32) {
        int kk = k0 + kh * 8;
        float4 a0 = *(const float4*)(arow + kk);
        float4 a1 = *(const float4*)(arow + kk + 4);
        bf16x8 af;
        af[0] = (__bf16)a0.x; af[1] = (__bf16)a0.y; af[2] = (__bf16)a0.z; af[3] = (__bf16)a0.w;
        af[4] = (__bf16)a1.x; af[5] = (__bf16)a1.y; af[6] = (__bf16)a1.z; af[7] = (__bf16)a1.w;
#pragma unroll
        for (int cb = 0; cb < 8; cb++) {
            bf16x8 bfA = *(const bf16x8*)(WA + (size_t)(cb * 16 + l16) * D_ + kk);
            accA[cb] = __builtin_amdgcn_mfma_f32_16x16x32_bf16(af, bfA, accA[cb], 0, 0, 0);
            bf16x8 bfB = *(const bf16x8*)(WB + (size_t)(cb * 16 + l16) * D_ + kk);
            accB[cb] = __builtin_amdgcn_mfma_f32_16x16x32_bf16(af, bfB, accB[cb], 0, 0, 0);
        }
    }
#pragma unroll
    for (int cb = 0; cb < 8; cb++) {
#pragma unroll
        for (int j = 0; j < 4; j++) {
            int r = row0 + kh * 4 + j;
            if (r < rows) {
                YA[(size_t)r * sA + cb * 16 + l16] = (__bf16)accA[cb][j];
                YB[(size_t)r * sB + cb * 16 + l16] = (__bf16)accB[cb][j];
            }
        }
    }
}

// ---------------- small GEMM: Y(rows x ncols, f32) = Xb(bf16, strided) @ P^T ----------------
__global__ __launch_bounds__(256) void gemm_pvk(const __bf16* __restrict__ Xb, int xstride,
                                                const __bf16* __restrict__ Pb,
                                                float* __restrict__ Y, int rows, int ncols) {
    int lane = threadIdx.x & 63;
    int wave = threadIdx.x >> 6;
    int row0 = blockIdx.x * 64 + wave * 16;
    if (row0 >= rows) return;
    int l16 = lane & 15, kh = lane >> 4;
    int ar = row0 + l16;
    int arc = ar < rows ? ar : rows - 1;
    const __bf16* arow = Xb + (size_t)arc * xstride;

    f32x4 acc[4] = {};
#pragma unroll
    for (int k0 = 0; k0 < D_; k0 += 32) {
        int kk = k0 + kh * 8;
        bf16x8 af = *(const bf16x8*)(arow + kk);
#pragma unroll
        for (int cb = 0; cb < 4; cb++) {
            int br = cb * 16 + l16;
            if (br >= ncols) br = ncols - 1;
            bf16x8 bf = *(const bf16x8*)(Pb + (size_t)br * D_ + kk);
            acc[cb] = __builtin_amdgcn_mfma_f32_16x16x32_bf16(af, bf, acc[cb], 0, 0, 0);
        }
    }
#pragma unroll
    for (int cb = 0; cb < 4; cb++) {
        int col = cb * 16 + l16;
        if (col >= ncols) continue;
#pragma unroll
        for (int j = 0; j < 4; j++) {
            int r = row0 + kh * 4 + j;
            if (r < rows) Y[(size_t)r * ncols + col] = acc[cb][j];
        }
    }
}

// ---------------- CSR build (combined users+items) ----------------
__global__ __launch_bounds__(256) void hist2(const int* __restrict__ eu, const int* __restrict__ ei,
                                             int* __restrict__ cnt_all, int nu, int E) {
    int e = blockIdx.x * 256 + threadIdx.x;
    if (e < E) {
        atomicAdd(&cnt_all[eu[e]], 1);
        atomicAdd(&cnt_all[nu + ei[e]], 1);
    }
}

__global__ __launch_bounds__(256) void scan_phaseA(const int* __restrict__ cnt, int* __restrict__ part, int n) {
    __shared__ int wsum[4];
    int t = threadIdx.x, lane = t & 63, w = t >> 6;
    int i0 = blockIdx.x * SCAN_TILE + t * SCAN_CH;
    int tot = 0;
#pragma unroll
    for (int j = 0; j < SCAN_CH; j++) tot += (i0 + j < n) ? cnt[i0 + j] : 0;
#pragma unroll
    for (int d = 32; d; d >>= 1) tot += __shfl_xor(tot, d);
    if (lane == 0) wsum[w] = tot;
    __syncthreads();
    if (t == 0) part[blockIdx.x] = wsum[0] + wsum[1] + wsum[2] + wsum[3];
}

__global__ __launch_bounds__(1024) void scan_phaseB(int* __restrict__ part, int nb,
                                                    int* __restrict__ off, int n) {
    __shared__ int wsum[16];
    int t = threadIdx.x, lane = t & 63, w = t >> 6;
    int v = (t < nb) ? part[t] : 0;
    int x = v;
#pragma unroll
    for (int d = 1; d < 64; d <<= 1) {
        int y = __shfl_up(x, d);
        if (lane >= d) x += y;
    }
    if (lane == 63) wsum[w] = x;
    __syncthreads();
    int wbase = 0;
    for (int ww = 0; ww < w; ww++) wbase += wsum[ww];
    if (t < nb) part[t] = wbase + x - v;
    if (t == 1023) off[n] = wbase + x;
}

__global__ __launch_bounds__(256) void scan_phaseC(const int* __restrict__ cnt, const int* __restrict__ part,
                                                   int* __restrict__ off, int* __restrict__ pos, int n) {
    __shared__ int wsum[4];
    int t = threadIdx.x, lane = t & 63, w = t >> 6;
    int i0 = blockIdx.x * SCAN_TILE + t * SCAN_CH;
    int loc[SCAN_CH];
    int tot = 0;
#pragma unroll
    for (int j = 0; j < SCAN_CH; j++) {
        int v = (i0 + j < n) ? cnt[i0 + j] : 0;
        loc[j] = tot; tot += v;
    }
    int x = tot;
#pragma unroll
    for (int d = 1; d < 64; d <<= 1) {
        int y = __shfl_up(x, d);
        if (lane >= d) x += y;
    }
    if (lane == 63) wsum[w] = x;
    __syncthreads();
    int wbase = 0;
    for (int ww = 0; ww < w; ww++) wbase += wsum[ww];
    int excl = part[blockIdx.x] + wbase + x - tot;
#pragma unroll
    for (int j = 0; j < SCAN_CH; j++) {
        if (i0 + j < n) { off[i0 + j] = excl + loc[j]; pos[i0 + j] = excl + loc[j]; }
    }
}

__global__ __launch_bounds__(256) void scatter2(const int* __restrict__ eu, const int* __restrict__ ei,
                                                int* __restrict__ pos_all, int* __restrict__ list_all,
                                                int nu, int E) {
    int e = blockIdx.x * 256 + threadIdx.x;
    if (e < E) {
        int pu = atomicAdd(&pos_all[eu[e]], 1);
        list_all[pu] = e;
        int pi = atomicAdd(&pos_all[nu + ei[e]], 1);
        list_all[pi] = e;
    }
}

// ---------------- fused per-user: inline logits + online softmax + messages ----------------
// u_rec: {um, umb, lu} stride 384; i_rec: {im, imb} stride 256
__global__ __launch_bounds__(256) void user_fused(const int* __restrict__ off_all, const int* __restrict__ list_all,
                                                  const int* __restrict__ ei, const int* __restrict__ rui,
                                                  const int* __restrict__ riu,
                                                  const __bf16* __restrict__ i_rec,
                                                  const __bf16* __restrict__ u_rec,
                                                  const __bf16* __restrict__ li,
                                                  const __bf16* __restrict__ pKb,
                                                  const float* __restrict__ upv,
                                                  float* __restrict__ hLu, float* __restrict__ hSu,
                                                  int nu, int umax) {
    int u = blockIdx.x * 4 + (threadIdx.x >> 6);
    if (u >= nu) return;
    int lane = threadIdx.x & 63;
    int g = lane >> 5, l32 = lane & 31;
    int off = off_all[u], n = off_all[u + 1] - off;
    if (n == 0) {
        if (lane < 32) {
            ((float4*)(hLu + (size_t)u * D_))[l32] = make_float4(0.f, 0.f, 0.f, 0.f);
            ((float4*)(hSu + (size_t)u * D_))[l32] = make_float4(0.f, 0.f, 0.f, 0.f);
        }
        return;
    }
    float um4[4], li4[4];
    unpack4(*(const bf16x4*)(u_rec + (size_t)u * 384 + l32 * 4), um4);
    unpack4(*(const bf16x4*)(li + (size_t)u * D_ + l32 * 4), li4);
    const float* upv_row = upv + (size_t)u * umax;

    float m1 = -INFINITY, s1 = 0.f, a1[4] = {};
    float m2 = -INFINITY, s2 = 0.f, a2[4] = {};
    for (int i = g; i < n; i += 2) {
        int e = list_all[off + i];
        int item = ei[e];
        const __bf16* ib = i_rec + (size_t)item * 256;
        bf16x4 imv  = ((const bf16x4*)ib)[l32];
        bf16x4 imbv = ((const bf16x4*)(ib + 128))[l32];
        bf16x4 pkv  = ((const bf16x4*)(pKb + (size_t)riu[e] * D_))[l32];
        float uv = upv_row[rui[e]];
        float fim[4], fimb[4], fpk[4];
        unpack4(imv, fim); unpack4(imbv, fimb); unpack4(pkv, fpk);
        float d1 = 0.f, d2 = 0.f;
#pragma unroll
        for (int j = 0; j < 4; j++) {
            d1 = fmaf(um4[j], fim[j], d1);
            d2 = fmaf(li4[j], fim[j], d2);
        }
#pragma unroll
        for (int d = 16; d; d >>= 1) {
            d1 += __shfl_xor(d1, d);
            d2 += __shfl_xor(d2, d);
        }
        float lg1 = (d1 + uv) * INV_SQRT_D;
        float lg2 = d2 * INV_SQRT_D;
        float mn = fmaxf(m1, lg1);
        float r  = __expf(m1 - mn);
        float w  = __expf(lg1 - mn);
        s1 = s1 * r + w; m1 = mn;
#pragma unroll
        for (int j = 0; j < 4; j++) a1[j] = fmaf(a1[j], r, w * (fimb[j] + fpk[j]));
        mn = fmaxf(m2, lg2);
        r  = __expf(m2 - mn);
        w  = __expf(lg2 - mn);
        s2 = s2 * r + w; m2 = mn;
#pragma unroll
        for (int j = 0; j < 4; j++) a2[j] = fmaf(a2[j], r, w * (fim[j] + 1.f));
    }
    // merge the two 32-lane groups (flash-merge)
    float mo = __shfl_xor(m1, 32);
    float mm = fmaxf(m1, mo);
    float r  = __expf(m1 - mm);
    s1 *= r;
#pragma unroll
    for (int j = 0; j < 4; j++) a1[j] *= r;
    s1 += __shfl_xor(s1, 32);
#pragma unroll
    for (int j = 0; j < 4; j++) a1[j] += __shfl_xor(a1[j], 32);
    mo = __shfl_xor(m2, 32);
    mm = fmaxf(m2, mo);
    r  = __expf(m2 - mm);
    s2 *= r;
#pragma unroll
    for (int j = 0; j < 4; j++) a2[j] *= r;
    s2 += __shfl_xor(s2, 32);
#pragma unroll
    for (int j = 0; j < 4; j++) a2[j] += __shfl_xor(a2[j], 32);

    float inv1 = 1.f / s1, inv2 = 1.f / s2;
    if (lane < 32) {
        ((float4*)(hLu + (size_t)u * D_))[l32] = make_float4(a1[0] * inv1, a1[1] * inv1, a1[2] * inv1, a1[3] * inv1);
        ((float4*)(hSu + (size_t)u * D_))[l32] = make_float4(a2[0] * inv2, a2[1] * inv2, a2[2] * inv2, a2[3] * inv2);
    }
}

// ---------------- fused per-item ----------------
__global__ __launch_bounds__(256) void item_fused(const int* __restrict__ off_all, const int* __restrict__ list_all,
                                                  const int* __restrict__ eu, const int* __restrict__ rui,
                                                  const int* __restrict__ riu,
                                                  const __bf16* __restrict__ i_rec,
                                                  const __bf16* __restrict__ u_rec,
                                                  const __bf16* __restrict__ pVb,
                                                  const float* __restrict__ ipk,
                                                  float* __restrict__ hLi, float* __restrict__ hSi,
                                                  int nu, int ni, int imax) {
    int it = blockIdx.x * 4 + (threadIdx.x >> 6);
    if (it >= ni) return;
    int lane = threadIdx.x & 63;
    int g = lane >> 5, l32 = lane & 31;
    int off = off_all[nu + it], n = off_all[nu + it + 1] - off;
    if (n == 0) {
        if (lane < 32) {
            ((float4*)(hLi + (size_t)it * D_))[l32] = make_float4(0.f, 0.f, 0.f, 0.f);
            ((float4*)(hSi + (size_t)it * D_))[l32] = make_float4(0.f, 0.f, 0.f, 0.f);
        }
        return;
    }
    float im4[4];
    unpack4(*(const bf16x4*)(i_rec + (size_t)it * 256 + l32 * 4), im4);
    const float* ipk_row = ipk + (size_t)it * imax;

    float m1 = -INFINITY, s1 = 0.f, a1[4] = {};
    float m2 = -INFINITY, s2 = 0.f, a2[4] = {};
    for (int i = g; i < n; i += 2) {
        int e = list_all[off + i];
        int user = eu[e];
        const __bf16* ub = u_rec + (size_t)user * 384;
        bf16x4 umv  = ((const bf16x4*)ub)[l32];
        bf16x4 umbv = ((const bf16x4*)(ub + 128))[l32];
        bf16x4 luv  = ((const bf16x4*)(ub + 256))[l32];
        bf16x4 pvv  = ((const bf16x4*)(pVb + (size_t)rui[e] * D_))[l32];
        float iv = ipk_row[riu[e]];
        float fum[4], fumb[4], flu[4], fpv[4];
        unpack4(umv, fum); unpack4(umbv, fumb); unpack4(luv, flu); unpack4(pvv, fpv);
        float d1 = 0.f, d2 = 0.f;
#pragma unroll
        for (int j = 0; j < 4; j++) {
            d1 = fmaf(fum[j], im4[j], d1);
            d2 = fmaf(flu[j], im4[j], d2);
        }
#pragma unroll
        for (int d = 16; d; d >>= 1) {
            d1 += __shfl_xor(d1, d);
            d2 += __shfl_xor(d2, d);
        }
        float lg1 = (d1 + iv) * INV_SQRT_D;
        float lg2 = d2 * INV_SQRT_D;
        float mn = fmaxf(m1, lg1);
        float r  = __expf(m1 - mn);
        float w  = __expf(lg1 - mn);
        s1 = s1 * r + w; m1 = mn;
#pragma unroll
        for (int j = 0; j < 4; j++) a1[j] = fmaf(a1[j], r, w * (fumb[j] + fpv[j]));
        mn = fmaxf(m2, lg2);
        r  = __expf(m2 - mn);
        w  = __expf(lg2 - mn);
        s2 = s2 * r + w; m2 = mn;
#pragma unroll
        for (int j = 0; j < 4; j++) a2[j] = fmaf(a2[j], r, w * (fum[j] + 1.f));
    }
    float mo = __shfl_xor(m1, 32);
    float mm = fmaxf(m1, mo);
    float r  = __expf(m1 - mm);
    s1 *= r;
#pragma unroll
    for (int j = 0; j < 4; j++) a1[j] *= r;
    s1 += __shfl_xor(s1, 32);
#pragma unroll
    for (int j = 0; j < 4; j++) a1[j] += __shfl_xor(a1[j], 32);
    mo = __shfl_xor(m2, 32);
    mm = fmaxf(m2, mo);
    r  = __expf(m2 - mm);
    s2 *= r;
#pragma unroll
    for (int j = 0; j < 4; j++) a2[j] *= r;
    s2 += __shfl_xor(s2, 32);
#pragma unroll
    for (int j = 0; j < 4; j++) a2[j] += __shfl_xor(a2[j], 32);

    float inv1 = 1.f / s1, inv2 = 1.f / s2;
    if (lane < 32) {
        ((float4*)(hLi + (size_t)it * D_))[l32] = make_float4(a1[0] * inv1, a1[1] * inv1, a1[2] * inv1, a1[3] * inv1);
        ((float4*)(hSi + (size_t)it * D_))[l32] = make_float4(a2[0] * inv2, a2[1] * inv2, a2[2] * inv2, a2[3] * inv2);
    }
}

extern "C" void kernel_launch(void* const* d_in, const int* in_sizes, int n_in,
                              void* d_out, int out_size, void* d_ws, size_t ws_size,
                              hipStream_t stream) {
    (void)n_in; (void)out_size; (void)ws_size;
    const float* u_emb = (const float*)d_in[0];
    const float* i_emb = (const float*)d_in[1];
    const int* edge_u = (const int*)d_in[2];
    const int* edge_i = (const int*)d_in[3];
    const int* rui = (const int*)d_in[4];
    const int* riu = (const int*)d_in[5];
    const int* last_u_items = (const int*)d_in[6];
    const int* last_i_users = (const int*)d_in[7];
    const float* W1  = (const float*)d_in[8];
    const float* W2  = (const float*)d_in[9];
    const float* W1b = (const float*)d_in[10];
    const float* W2b = (const float*)d_in[11];
    const float* W3  = (const float*)d_in[12];
    const float* W4  = (const float*)d_in[13];
    const float* pV  = (const float*)d_in[14];
    const float* pK  = (const float*)d_in[15];
    const float* last_user_table = (const float*)d_in[16];
    const float* last_item_table = (const float*)d_in[17];

    const int NU = in_sizes[0] / D_;
    const int NI = in_sizes[1] / D_;
    const int E  = in_sizes[2];
    const int UMAXr = in_sizes[14] / D_;
    const int IMAXr = in_sizes[15] / D_;
    const int NSEG = NU + NI;

    size_t cur = 0;
    auto alloc = [&](size_t bytes) -> void* {
        void* p = (char*)d_ws + cur;
        cur += (bytes + 255) & ~(size_t)255;
        return p;
    };

    __bf16* Wb    = (__bf16*)alloc(6 * 16384 * sizeof(__bf16));
    __bf16* pVb   = (__bf16*)alloc((size_t)UMAXr * D_ * 2);
    __bf16* pKb   = (__bf16*)alloc((size_t)IMAXr * D_ * 2);
    __bf16* i_rec = (__bf16*)alloc((size_t)NI * 256 * 2);   // {im, imb}
    __bf16* u_rec = (__bf16*)alloc((size_t)NU * 384 * 2);   // {um, umb, lu}
    __bf16* li_bf = (__bf16*)alloc((size_t)NU * D_ * 2);
    float* upv   = (float*)alloc((size_t)NU * UMAXr * 4);
    float* ipk   = (float*)alloc((size_t)NI * IMAXr * 4);
    int* cnt_all  = (int*)alloc((size_t)NSEG * 4);
    int* off_all  = (int*)alloc((size_t)(NSEG + 1) * 4);
    int* pos_all  = (int*)alloc((size_t)NSEG * 4);
    int* list_all = (int*)alloc((size_t)2 * E * 4);
    int* parts    = (int*)alloc(1024 * 4);

    float* out = (float*)d_out;
    float* hLu = out;
    float* hSu = out + (size_t)NU * D_;
    float* hLi = out + (size_t)2 * NU * D_;
    float* hSi = out + (size_t)2 * NU * D_ + (size_t)NI * D_;

    // weights -> bf16
    W6 w6;
    w6.p[0] = W1; w6.p[1] = W2; w6.p[2] = W1b; w6.p[3] = W2b; w6.p[4] = W3; w6.p[5] = W4;
    cvt_weights<<<(6 * 16384 + 255) / 256, 256, 0, stream>>>(w6, Wb);
    cvt2<<<(UMAXr * D_ + 255) / 256, 256, 0, stream>>>(pV, pK, pVb, pKb, UMAXr * D_);

    // CSR build (combined users+items, multi-block scan)
    hipMemsetAsync(cnt_all, 0, (size_t)NSEG * 4, stream);
    hist2<<<(E + 255) / 256, 256, 0, stream>>>(edge_u, edge_i, cnt_all, NU, E);
    int nb = (NSEG + SCAN_TILE - 1) / SCAN_TILE;
    scan_phaseA<<<nb, 256, 0, stream>>>(cnt_all, parts, NSEG);
    scan_phaseB<<<1, 1024, 0, stream>>>(parts, nb, off_all, NSEG);
    scan_phaseC<<<nb, 256, 0, stream>>>(cnt_all, parts, off_all, pos_all, NSEG);
    scatter2<<<(E + 255) / 256, 256, 0, stream>>>(edge_u, edge_i, pos_all, list_all, NU, E);

    // GEMMs into packed records
    int gu = (NU + 63) / 64, gi = (NI + 63) / 64;
    gemm_dual<<<gi, 256, 0, stream>>>(i_emb, Wb + 0 * 16384, Wb + 2 * 16384,
                                      i_rec + 0, 256, i_rec + 128, 256, NI);     // im, imb
    gemm_dual<<<gu, 256, 0, stream>>>(u_emb, Wb + 1 * 16384, Wb + 3 * 16384,
                                      u_rec + 0, 384, u_rec + 128, 384, NU);     // um, umb
    gemm_xwt<<<gu, 256, 0, stream>>>(last_item_table, last_u_items, Wb + 4 * 16384, li_bf, 128, NU); // li
    gemm_xwt<<<gu, 256, 0, stream>>>(last_user_table, last_i_users, Wb + 5 * 16384, u_rec + 256, 384, NU); // lu

    // positional-dot tables
    gemm_pvk<<<gu, 256, 0, stream>>>(u_rec, 384, pVb, upv, NU, UMAXr);
    gemm_pvk<<<gi, 256, 0, stream>>>(i_rec, 256, pKb, ipk, NI, IMAXr);

    // fused softmax + message passing
    user_fused<<<(NU + 3) / 4, 256, 0, stream>>>(off_all, list_all, edge_i, rui, riu,
                                                 i_rec, u_rec, li_bf, pKb, upv, hLu, hSu, NU, UMAXr);
    item_fused<<<(NI + 3) / 4, 256, 0, stream>>>(off_all, list_all, edge_u, rui, riu,
                                                 i_rec, u_rec, pVb, ipk, hLi, hSi, NU, NI, IMAXr);
}

// Round 5
// 495.513 us; speedup vs baseline: 1.7928x; 1.0044x over previous
//
#include <hip/hip_runtime.h>
#include <hip/hip_bf16.h>
#include <math.h>

#define D_ 128
#define INV_SQRT_D 0.08838834764831845f
#define SCAN_CH 16
#define SCAN_TILE (256 * SCAN_CH)   // 4096 elements per block

typedef __bf16 bf16x8 __attribute__((ext_vector_type(8)));
typedef float f32x4 __attribute__((ext_vector_type(4)));

struct W6 { const float* p[6]; };

__device__ __forceinline__ void unpack8(bf16x8 v, float* f) {
    const uint32_t* u = (const uint32_t*)&v;
#pragma unroll
    for (int i = 0; i < 4; i++) {
        uint32_t w = u[i];
        f[2 * i]     = __uint_as_float(w << 16);
        f[2 * i + 1] = __uint_as_float(w & 0xffff0000u);
    }
}

// ---------------- weight f32 -> bf16 ----------------
__global__ __launch_bounds__(256) void cvt_weights(W6 w, __bf16* __restrict__ out) {
    int idx = blockIdx.x * 256 + threadIdx.x;
    if (idx >= 6 * 16384) return;
    out[idx] = (__bf16)w.p[idx >> 14][idx & 16383];
}

__global__ __launch_bounds__(256) void cvt2(const float* __restrict__ a, const float* __restrict__ b,
                                            __bf16* __restrict__ oa, __bf16* __restrict__ ob, int n) {
    int idx = blockIdx.x * 256 + threadIdx.x;
    if (idx < n) { oa[idx] = (__bf16)a[idx]; ob[idx] = (__bf16)b[idx]; }
}

// ---------------- GEMM: Y = X[gidx] @ W^T, strided output ----------------
__global__ __launch_bounds__(256) void gemm_xwt(const float* __restrict__ X,
                                                const int* __restrict__ gidx,
                                                const __bf16* __restrict__ Wb,
                                                __bf16* __restrict__ Y, int ystride, int rows) {
    int lane = threadIdx.x & 63;
    int wave = threadIdx.x >> 6;
    int row0 = blockIdx.x * 64 + wave * 16;
    if (row0 >= rows) return;
    int l16 = lane & 15, kh = lane >> 4;
    int ar = row0 + l16;
    int arc = ar < rows ? ar : rows - 1;
    long srcrow = gidx ? (long)gidx[arc] : (long)arc;
    const float* arow = X + (size_t)srcrow * D_;

    f32x4 acc[8] = {};
#pragma unroll
    for (int k0 = 0; k0 < D_; k0 += 32) {
        int kk = k0 + kh * 8;
        float4 a0 = *(const float4*)(arow + kk);
        float4 a1 = *(const float4*)(arow + kk + 4);
        bf16x8 af;
        af[0] = (__bf16)a0.x; af[1] = (__bf16)a0.y; af[2] = (__bf16)a0.z; af[3] = (__bf16)a0.w;
        af[4] = (__bf16)a1.x; af[5] = (__bf16)a1.y; af[6] = (__bf16)a1.z; af[7] = (__bf16)a1.w;
#pragma unroll
        for (int cb = 0; cb < 8; cb++) {
            bf16x8 bf = *(const bf16x8*)(Wb + (size_t)(cb * 16 + l16) * D_ + kk);
            acc[cb] = __builtin_amdgcn_mfma_f32_16x16x32_bf16(af, bf, acc[cb], 0, 0, 0);
        }
    }
#pragma unroll
    for (int cb = 0; cb < 8; cb++) {
#pragma unroll
        for (int j = 0; j < 4; j++) {
            int r = row0 + kh * 4 + j;
            if (r < rows) Y[(size_t)r * ystride + cb * 16 + l16] = (__bf16)acc[cb][j];
        }
    }
}

// ---------------- GEMM dual: YA = X @ WA^T, YB = X @ WB^T (shared X read), strided ----------------
__global__ __launch_bounds__(256) void gemm_dual(const float* __restrict__ X,
                                                 const __bf16* __restrict__ WA,
                                                 const __bf16* __restrict__ WB,
                                                 __bf16* __restrict__ YA, int sA,
                                                 __bf16* __restrict__ YB, int sB, int rows) {
    int lane = threadIdx.x & 63;
    int wave = threadIdx.x >> 6;
    int row0 = blockIdx.x * 64 + wave * 16;
    if (row0 >= rows) return;
    int l16 = lane & 15, kh = lane >> 4;
    int ar = row0 + l16;
    int arc = ar < rows ? ar : rows - 1;
    const float* arow = X + (size_t)arc * D_;

    f32x4 accA[8] = {}, accB[8] = {};
#pragma unroll
    for (int k0 = 0; k0 < D_; k0 += 32) {
        int kk = k0 + kh * 8;
        float4 a0 = *(const float4*)(arow + kk);
        float4 a1 = *(const float4*)(arow + kk + 4);
        bf16x8 af;
        af[0] = (__bf16)a0.x; af[1] = (__bf16)a0.y; af[2] = (__bf16)a0.z; af[3] = (__bf16)a0.w;
        af[4] = (__bf16)a1.x; af[5] = (__bf16)a1.y; af[6] = (__bf16)a1.z; af[7] = (__bf16)a1.w;
#pragma unroll
        for (int cb = 0; cb < 8; cb++) {
            bf16x8 bfA = *(const bf16x8*)(WA + (size_t)(cb * 16 + l16) * D_ + kk);
            accA[cb] = __builtin_amdgcn_mfma_f32_16x16x32_bf16(af, bfA, accA[cb], 0, 0, 0);
            bf16x8 bfB = *(const bf16x8*)(WB + (size_t)(cb * 16 + l16) * D_ + kk);
            accB[cb] = __builtin_amdgcn_mfma_f32_16x16x32_bf16(af, bfB, accB[cb], 0, 0, 0);
        }
    }
#pragma unroll
    for (int cb = 0; cb < 8; cb++) {
#pragma unroll
        for (int j = 0; j < 4; j++) {
            int r = row0 + kh * 4 + j;
            if (r < rows) {
                YA[(size_t)r * sA + cb * 16 + l16] = (__bf16)accA[cb][j];
                YB[(size_t)r * sB + cb * 16 + l16] = (__bf16)accB[cb][j];
            }
        }
    }
}

// ---------------- small GEMM: Y = (Xb @ P^T) * INV_SQRT_D ----------------
__global__ __launch_bounds__(256) void gemm_pvk(const __bf16* __restrict__ Xb, int xstride,
                                                const __bf16* __restrict__ Pb,
                                                float* __restrict__ Y, int rows, int ncols) {
    int lane = threadIdx.x & 63;
    int wave = threadIdx.x >> 6;
    int row0 = blockIdx.x * 64 + wave * 16;
    if (row0 >= rows) return;
    int l16 = lane & 15, kh = lane >> 4;
    int ar = row0 + l16;
    int arc = ar < rows ? ar : rows - 1;
    const __bf16* arow = Xb + (size_t)arc * xstride;

    f32x4 acc[4] = {};
#pragma unroll
    for (int k0 = 0; k0 < D_; k0 += 32) {
        int kk = k0 + kh * 8;
        bf16x8 af = *(const bf16x8*)(arow + kk);
#pragma unroll
        for (int cb = 0; cb < 4; cb++) {
            int br = cb * 16 + l16;
            if (br >= ncols) br = ncols - 1;
            bf16x8 bf = *(const bf16x8*)(Pb + (size_t)br * D_ + kk);
            acc[cb] = __builtin_amdgcn_mfma_f32_16x16x32_bf16(af, bf, acc[cb], 0, 0, 0);
        }
    }
#pragma unroll
    for (int cb = 0; cb < 4; cb++) {
        int col = cb * 16 + l16;
        if (col >= ncols) continue;
#pragma unroll
        for (int j = 0; j < 4; j++) {
            int r = row0 + kh * 4 + j;
            if (r < rows) Y[(size_t)r * ncols + col] = acc[cb][j] * INV_SQRT_D;
        }
    }
}

// ---------------- CSR build (combined users+items) ----------------
__global__ __launch_bounds__(256) void hist2(const int* __restrict__ eu, const int* __restrict__ ei,
                                             int* __restrict__ cnt_all, int nu, int E) {
    int e = blockIdx.x * 256 + threadIdx.x;
    if (e < E) {
        atomicAdd(&cnt_all[eu[e]], 1);
        atomicAdd(&cnt_all[nu + ei[e]], 1);
    }
}

__global__ __launch_bounds__(256) void scan_phaseA(const int* __restrict__ cnt, int* __restrict__ part, int n) {
    __shared__ int wsum[4];
    int t = threadIdx.x, lane = t & 63, w = t >> 6;
    int i0 = blockIdx.x * SCAN_TILE + t * SCAN_CH;
    int tot = 0;
#pragma unroll
    for (int j = 0; j < SCAN_CH; j++) tot += (i0 + j < n) ? cnt[i0 + j] : 0;
#pragma unroll
    for (int d = 32; d; d >>= 1) tot += __shfl_xor(tot, d);
    if (lane == 0) wsum[w] = tot;
    __syncthreads();
    if (t == 0) part[blockIdx.x] = wsum[0] + wsum[1] + wsum[2] + wsum[3];
}

__global__ __launch_bounds__(1024) void scan_phaseB(int* __restrict__ part, int nb,
                                                    int* __restrict__ off, int n) {
    __shared__ int wsum[16];
    int t = threadIdx.x, lane = t & 63, w = t >> 6;
    int v = (t < nb) ? part[t] : 0;
    int x = v;
#pragma unroll
    for (int d = 1; d < 64; d <<= 1) {
        int y = __shfl_up(x, d);
        if (lane >= d) x += y;
    }
    if (lane == 63) wsum[w] = x;
    __syncthreads();
    int wbase = 0;
    for (int ww = 0; ww < w; ww++) wbase += wsum[ww];
    if (t < nb) part[t] = wbase + x - v;
    if (t == 1023) off[n] = wbase + x;
}

__global__ __launch_bounds__(256) void scan_phaseC(const int* __restrict__ cnt, const int* __restrict__ part,
                                                   int* __restrict__ off, int* __restrict__ pos, int n) {
    __shared__ int wsum[4];
    int t = threadIdx.x, lane = t & 63, w = t >> 6;
    int i0 = blockIdx.x * SCAN_TILE + t * SCAN_CH;
    int loc[SCAN_CH];
    int tot = 0;
#pragma unroll
    for (int j = 0; j < SCAN_CH; j++) {
        int v = (i0 + j < n) ? cnt[i0 + j] : 0;
        loc[j] = tot; tot += v;
    }
    int x = tot;
#pragma unroll
    for (int d = 1; d < 64; d <<= 1) {
        int y = __shfl_up(x, d);
        if (lane >= d) x += y;
    }
    if (lane == 63) wsum[w] = x;
    __syncthreads();
    int wbase = 0;
    for (int ww = 0; ww < w; ww++) wbase += wsum[ww];
    int excl = part[blockIdx.x] + wbase + x - tot;
#pragma unroll
    for (int j = 0; j < SCAN_CH; j++) {
        if (i0 + j < n) { off[i0 + j] = excl + loc[j]; pos[i0 + j] = excl + loc[j]; }
    }
}

__global__ __launch_bounds__(256) void scatter2(const int* __restrict__ eu, const int* __restrict__ ei,
                                                int* __restrict__ pos_all, int* __restrict__ list_all,
                                                int nu, int E) {
    int e = blockIdx.x * 256 + threadIdx.x;
    if (e < E) {
        int pu = atomicAdd(&pos_all[eu[e]], 1);
        list_all[pu] = e;
        int pi = atomicAdd(&pos_all[nu + ei[e]], 1);
        list_all[pi] = e;
    }
}

// ---------------- fused per-user: all 3 logit dots here (um/li/lu in regs) ----------------
// i_rec: {im, imb} stride 256. Writes mb_val[e] = {mm_scaled, b_scaled} for item pass.
__global__ __launch_bounds__(256) void user_fused(const int* __restrict__ off_all, const int* __restrict__ list_all,
                                                  const int* __restrict__ ei, const int* __restrict__ rui,
                                                  const int* __restrict__ riu,
                                                  const __bf16* __restrict__ i_rec,
                                                  const __bf16* __restrict__ u_rec,
                                                  const __bf16* __restrict__ li_t,
                                                  const __bf16* __restrict__ lu_t,
                                                  const __bf16* __restrict__ pKb,
                                                  const float* __restrict__ upv,
                                                  float2* __restrict__ mb_val,
                                                  float* __restrict__ hLu, float* __restrict__ hSu,
                                                  int nu, int umax) {
    int u = blockIdx.x * 4 + (threadIdx.x >> 6);
    if (u >= nu) return;
    int lane = threadIdx.x & 63;
    int g = lane >> 4, l16 = lane & 15;
    int off = off_all[u], n = off_all[u + 1] - off;
    if (n == 0) {
        if (lane < 16) {
            float4 z = make_float4(0.f, 0.f, 0.f, 0.f);
            ((float4*)(hLu + (size_t)u * D_ + l16 * 8))[0] = z;
            ((float4*)(hLu + (size_t)u * D_ + l16 * 8))[1] = z;
            ((float4*)(hSu + (size_t)u * D_ + l16 * 8))[0] = z;
            ((float4*)(hSu + (size_t)u * D_ + l16 * 8))[1] = z;
        }
        return;
    }
    float um8[8], li8[8], lu8[8];
    unpack8(((const bf16x8*)(u_rec + (size_t)u * 256))[l16], um8);
    unpack8(((const bf16x8*)(li_t + (size_t)u * D_))[l16], li8);
    unpack8(((const bf16x8*)(lu_t + (size_t)u * D_))[l16], lu8);
#pragma unroll
    for (int j = 0; j < 8; j++) { um8[j] *= INV_SQRT_D; li8[j] *= INV_SQRT_D; lu8[j] *= INV_SQRT_D; }
    const float* upv_row = upv + (size_t)u * umax;

    float s1 = 0.f, s2 = 0.f, a1[8] = {}, a2[8] = {};
    for (int i = g; i < n; i += 4) {
        int e = list_all[off + i];
        int item = ei[e];
        const __bf16* ib = i_rec + (size_t)item * 256;
        bf16x8 imv  = ((const bf16x8*)ib)[l16];
        bf16x8 imbv = ((const bf16x8*)(ib + 128))[l16];
        bf16x8 pkv  = ((const bf16x8*)(pKb + (size_t)riu[e] * D_))[l16];
        float fim[8], fimb[8], fpk[8];
        unpack8(imv, fim); unpack8(imbv, fimb); unpack8(pkv, fpk);
        float d1 = 0.f, d2 = 0.f, d3 = 0.f;
#pragma unroll
        for (int j = 0; j < 8; j++) {
            d1 = fmaf(um8[j], fim[j], d1);
            d2 = fmaf(li8[j], fim[j], d2);
            d3 = fmaf(lu8[j], fim[j], d3);
        }
#pragma unroll
        for (int d = 1; d < 16; d <<= 1) {
            d1 += __shfl_xor(d1, d);
            d2 += __shfl_xor(d2, d);
            d3 += __shfl_xor(d3, d);
        }
        if (l16 == 0) mb_val[e] = make_float2(d1, d3);
        float w1 = __expf(d1 + upv_row[rui[e]]);
        float w2 = __expf(d2);
        s1 += w1; s2 += w2;
#pragma unroll
        for (int j = 0; j < 8; j++) {
            a1[j] = fmaf(w1, fimb[j] + fpk[j], a1[j]);
            a2[j] = fmaf(w2, fim[j], a2[j]);
        }
    }
    // merge 4 groups
#pragma unroll
    for (int d = 16; d < 64; d <<= 1) {
        s1 += __shfl_xor(s1, d); s2 += __shfl_xor(s2, d);
#pragma unroll
        for (int j = 0; j < 8; j++) {
            a1[j] += __shfl_xor(a1[j], d);
            a2[j] += __shfl_xor(a2[j], d);
        }
    }
    if (lane < 16) {
        float inv1 = 1.f / s1, inv2 = 1.f / s2;
        ((float4*)(hLu + (size_t)u * D_ + l16 * 8))[0] = make_float4(a1[0]*inv1, a1[1]*inv1, a1[2]*inv1, a1[3]*inv1);
        ((float4*)(hLu + (size_t)u * D_ + l16 * 8))[1] = make_float4(a1[4]*inv1, a1[5]*inv1, a1[6]*inv1, a1[7]*inv1);
        ((float4*)(hSu + (size_t)u * D_ + l16 * 8))[0] = make_float4(a2[0]*inv2+1.f, a2[1]*inv2+1.f, a2[2]*inv2+1.f, a2[3]*inv2+1.f);
        ((float4*)(hSu + (size_t)u * D_ + l16 * 8))[1] = make_float4(a2[4]*inv2+1.f, a2[5]*inv2+1.f, a2[6]*inv2+1.f, a2[7]*inv2+1.f);
    }
}

// ---------------- fused per-item: no dots, logits from mb_val + ipk ----------------
__global__ __launch_bounds__(256) void item_fused(const int* __restrict__ off_all, const int* __restrict__ list_all,
                                                  const int* __restrict__ eu, const int* __restrict__ rui,
                                                  const int* __restrict__ riu,
                                                  const __bf16* __restrict__ u_rec,
                                                  const __bf16* __restrict__ pVb,
                                                  const float* __restrict__ ipk,
                                                  const float2* __restrict__ mb_val,
                                                  float* __restrict__ hLi, float* __restrict__ hSi,
                                                  int nu, int ni, int imax) {
    int it = blockIdx.x * 4 + (threadIdx.x >> 6);
    if (it >= ni) return;
    int lane = threadIdx.x & 63;
    int g = lane >> 4, l16 = lane & 15;
    int off = off_all[nu + it], n = off_all[nu + it + 1] - off;
    if (n == 0) {
        if (lane < 16) {
            float4 z = make_float4(0.f, 0.f, 0.f, 0.f);
            ((float4*)(hLi + (size_t)it * D_ + l16 * 8))[0] = z;
            ((float4*)(hLi + (size_t)it * D_ + l16 * 8))[1] = z;
            ((float4*)(hSi + (size_t)it * D_ + l16 * 8))[0] = z;
            ((float4*)(hSi + (size_t)it * D_ + l16 * 8))[1] = z;
        }
        return;
    }
    const float* ipk_row = ipk + (size_t)it * imax;

    float s1 = 0.f, s2 = 0.f, a1[8] = {}, a2[8] = {};
    for (int i = g; i < n; i += 4) {
        int e = list_all[off + i];
        int user = eu[e];
        float2 mb = mb_val[e];
        const __bf16* ub = u_rec + (size_t)user * 256;
        bf16x8 umv  = ((const bf16x8*)ub)[l16];
        bf16x8 umbv = ((const bf16x8*)(ub + 128))[l16];
        bf16x8 pvv  = ((const bf16x8*)(pVb + (size_t)rui[e] * D_))[l16];
        float fum[8], fumb[8], fpv[8];
        unpack8(umv, fum); unpack8(umbv, fumb); unpack8(pvv, fpv);
        float w1 = __expf(mb.x + ipk_row[riu[e]]);
        float w2 = __expf(mb.y);
        s1 += w1; s2 += w2;
#pragma unroll
        for (int j = 0; j < 8; j++) {
            a1[j] = fmaf(w1, fumb[j] + fpv[j], a1[j]);
            a2[j] = fmaf(w2, fum[j], a2[j]);
        }
    }
#pragma unroll
    for (int d = 16; d < 64; d <<= 1) {
        s1 += __shfl_xor(s1, d); s2 += __shfl_xor(s2, d);
#pragma unroll
        for (int j = 0; j < 8; j++) {
            a1[j] += __shfl_xor(a1[j], d);
            a2[j] += __shfl_xor(a2[j], d);
        }
    }
    if (lane < 16) {
        float inv1 = 1.f / s1, inv2 = 1.f / s2;
        ((float4*)(hLi + (size_t)it * D_ + l16 * 8))[0] = make_float4(a1[0]*inv1, a1[1]*inv1, a1[2]*inv1, a1[3]*inv1);
        ((float4*)(hLi + (size_t)it * D_ + l16 * 8))[1] = make_float4(a1[4]*inv1, a1[5]*inv1, a1[6]*inv1, a1[7]*inv1);
        ((float4*)(hSi + (size_t)it * D_ + l16 * 8))[0] = make_float4(a2[0]*inv2+1.f, a2[1]*inv2+1.f, a2[2]*inv2+1.f, a2[3]*inv2+1.f);
        ((float4*)(hSi + (size_t)it * D_ + l16 * 8))[1] = make_float4(a2[4]*inv2+1.f, a2[5]*inv2+1.f, a2[6]*inv2+1.f, a2[7]*inv2+1.f);
    }
}

extern "C" void kernel_launch(void* const* d_in, const int* in_sizes, int n_in,
                              void* d_out, int out_size, void* d_ws, size_t ws_size,
                              hipStream_t stream) {
    (void)n_in; (void)out_size; (void)ws_size;
    const float* u_emb = (const float*)d_in[0];
    const float* i_emb = (const float*)d_in[1];
    const int* edge_u = (const int*)d_in[2];
    const int* edge_i = (const int*)d_in[3];
    const int* rui = (const int*)d_in[4];
    const int* riu = (const int*)d_in[5];
    const int* last_u_items = (const int*)d_in[6];
    const int* last_i_users = (const int*)d_in[7];
    const float* W1  = (const float*)d_in[8];
    const float* W2  = (const float*)d_in[9];
    const float* W1b = (const float*)d_in[10];
    const float* W2b = (const float*)d_in[11];
    const float* W3  = (const float*)d_in[12];
    const float* W4  = (const float*)d_in[13];
    const float* pV  = (const float*)d_in[14];
    const float* pK  = (const float*)d_in[15];
    const float* last_user_table = (const float*)d_in[16];
    const float* last_item_table = (const float*)d_in[17];

    const int NU = in_sizes[0] / D_;
    const int NI = in_sizes[1] / D_;
    const int E  = in_sizes[2];
    const int UMAXr = in_sizes[14] / D_;
    const int IMAXr = in_sizes[15] / D_;
    const int NSEG = NU + NI;

    size_t cur = 0;
    auto alloc = [&](size_t bytes) -> void* {
        void* p = (char*)d_ws + cur;
        cur += (bytes + 255) & ~(size_t)255;
        return p;
    };

    __bf16* Wb    = (__bf16*)alloc(6 * 16384 * sizeof(__bf16));
    __bf16* pVb   = (__bf16*)alloc((size_t)UMAXr * D_ * 2);
    __bf16* pKb   = (__bf16*)alloc((size_t)IMAXr * D_ * 2);
    __bf16* i_rec = (__bf16*)alloc((size_t)NI * 256 * 2);   // {im, imb}
    __bf16* u_rec = (__bf16*)alloc((size_t)NU * 256 * 2);   // {um, umb}
    __bf16* li_bf = (__bf16*)alloc((size_t)NU * D_ * 2);
    __bf16* lu_bf = (__bf16*)alloc((size_t)NU * D_ * 2);
    float* upv    = (float*)alloc((size_t)NU * UMAXr * 4);
    float* ipk    = (float*)alloc((size_t)NI * IMAXr * 4);
    float2* mb_val = (float2*)alloc((size_t)E * 8);
    int* cnt_all  = (int*)alloc((size_t)NSEG * 4);
    int* off_all  = (int*)alloc((size_t)(NSEG + 1) * 4);
    int* pos_all  = (int*)alloc((size_t)NSEG * 4);
    int* list_all = (int*)alloc((size_t)2 * E * 4);
    int* parts    = (int*)alloc(1024 * 4);

    float* out = (float*)d_out;
    float* hLu = out;
    float* hSu = out + (size_t)NU * D_;
    float* hLi = out + (size_t)2 * NU * D_;
    float* hSi = out + (size_t)2 * NU * D_ + (size_t)NI * D_;

    // weights -> bf16
    W6 w6;
    w6.p[0] = W1; w6.p[1] = W2; w6.p[2] = W1b; w6.p[3] = W2b; w6.p[4] = W3; w6.p[5] = W4;
    cvt_weights<<<(6 * 16384 + 255) / 256, 256, 0, stream>>>(w6, Wb);
    cvt2<<<(UMAXr * D_ + 255) / 256, 256, 0, stream>>>(pV, pK, pVb, pKb, UMAXr * D_);

    // CSR build (combined users+items, multi-block scan)
    hipMemsetAsync(cnt_all, 0, (size_t)NSEG * 4, stream);
    hist2<<<(E + 255) / 256, 256, 0, stream>>>(edge_u, edge_i, cnt_all, NU, E);
    int nb = (NSEG + SCAN_TILE - 1) / SCAN_TILE;
    scan_phaseA<<<nb, 256, 0, stream>>>(cnt_all, parts, NSEG);
    scan_phaseB<<<1, 1024, 0, stream>>>(parts, nb, off_all, NSEG);
    scan_phaseC<<<nb, 256, 0, stream>>>(cnt_all, parts, off_all, pos_all, NSEG);
    scatter2<<<(E + 255) / 256, 256, 0, stream>>>(edge_u, edge_i, pos_all, list_all, NU, E);

    // GEMMs into packed records
    int gu = (NU + 63) / 64, gi = (NI + 63) / 64;
    gemm_dual<<<gi, 256, 0, stream>>>(i_emb, Wb + 0 * 16384, Wb + 2 * 16384,
                                      i_rec + 0, 256, i_rec + 128, 256, NI);     // im, imb
    gemm_dual<<<gu, 256, 0, stream>>>(u_emb, Wb + 1 * 16384, Wb + 3 * 16384,
                                      u_rec + 0, 256, u_rec + 128, 256, NU);     // um, umb
    gemm_xwt<<<gu, 256, 0, stream>>>(last_item_table, last_u_items, Wb + 4 * 16384, li_bf, 128, NU); // li
    gemm_xwt<<<gu, 256, 0, stream>>>(last_user_table, last_i_users, Wb + 5 * 16384, lu_bf, 128, NU); // lu

    // positional-dot tables (pre-scaled by 1/sqrt(D))
    gemm_pvk<<<gu, 256, 0, stream>>>(u_rec, 256, pVb, upv, NU, UMAXr);
    gemm_pvk<<<gi, 256, 0, stream>>>(i_rec, 256, pKb, ipk, NI, IMAXr);

    // fused softmax + message passing (user first: produces mb_val for item pass)
    user_fused<<<(NU + 3) / 4, 256, 0, stream>>>(off_all, list_all, edge_i, rui, riu,
                                                 i_rec, u_rec, li_bf, lu_bf, pKb, upv, mb_val,
                                                 hLu, hSu, NU, UMAXr);
    item_fused<<<(NI + 3) / 4, 256, 0, stream>>>(off_all, list_all, edge_u, rui, riu,
                                                 u_rec, pVb, ipk, mb_val,
                                                 hLi, hSi, NU, NI, IMAXr);
}

// Round 6
// 489.298 us; speedup vs baseline: 1.8156x; 1.0127x over previous
//
#include <hip/hip_runtime.h>
#include <hip/hip_bf16.h>
#include <math.h>

#define D_ 128
#define INV_SQRT_D 0.08838834764831845f
#define SCAN_CH 16
#define SCAN_TILE (256 * SCAN_CH)   // 4096 elements per block

typedef __bf16 bf16x8 __attribute__((ext_vector_type(8)));
typedef float f32x4 __attribute__((ext_vector_type(4)));

struct W6 { const float* p[6]; };

__device__ __forceinline__ void unpack8(bf16x8 v, float* f) {
    const uint32_t* u = (const uint32_t*)&v;
#pragma unroll
    for (int i = 0; i < 4; i++) {
        uint32_t w = u[i];
        f[2 * i]     = __uint_as_float(w << 16);
        f[2 * i + 1] = __uint_as_float(w & 0xffff0000u);
    }
}

// ---------------- weight f32 -> bf16 ----------------
__global__ __launch_bounds__(256) void cvt_weights(W6 w, __bf16* __restrict__ out) {
    int idx = blockIdx.x * 256 + threadIdx.x;
    if (idx >= 6 * 16384) return;
    out[idx] = (__bf16)w.p[idx >> 14][idx & 16383];
}

__global__ __launch_bounds__(256) void cvt2(const float* __restrict__ a, const float* __restrict__ b,
                                            __bf16* __restrict__ oa, __bf16* __restrict__ ob, int n) {
    int idx = blockIdx.x * 256 + threadIdx.x;
    if (idx < n) { oa[idx] = (__bf16)a[idx]; ob[idx] = (__bf16)b[idx]; }
}

// ---------------- GEMM dual: YA = X @ WA^T, YB = X @ WB^T (shared X read), strided ----------------
__global__ __launch_bounds__(256) void gemm_dual(const float* __restrict__ X,
                                                 const __bf16* __restrict__ WA,
                                                 const __bf16* __restrict__ WB,
                                                 __bf16* __restrict__ YA, int sA,
                                                 __bf16* __restrict__ YB, int sB, int rows) {
    int lane = threadIdx.x & 63;
    int wave = threadIdx.x >> 6;
    int row0 = blockIdx.x * 64 + wave * 16;
    if (row0 >= rows) return;
    int l16 = lane & 15, kh = lane >> 4;
    int ar = row0 + l16;
    int arc = ar < rows ? ar : rows - 1;
    const float* arow = X + (size_t)arc * D_;

    f32x4 accA[8] = {}, accB[8] = {};
#pragma unroll
    for (int k0 = 0; k0 < D_; k0 += 32) {
        int kk = k0 + kh * 8;
        float4 a0 = *(const float4*)(arow + kk);
        float4 a1 = *(const float4*)(arow + kk + 4);
        bf16x8 af;
        af[0] = (__bf16)a0.x; af[1] = (__bf16)a0.y; af[2] = (__bf16)a0.z; af[3] = (__bf16)a0.w;
        af[4] = (__bf16)a1.x; af[5] = (__bf16)a1.y; af[6] = (__bf16)a1.z; af[7] = (__bf16)a1.w;
#pragma unroll
        for (int cb = 0; cb < 8; cb++) {
            bf16x8 bfA = *(const bf16x8*)(WA + (size_t)(cb * 16 + l16) * D_ + kk);
            accA[cb] = __builtin_amdgcn_mfma_f32_16x16x32_bf16(af, bfA, accA[cb], 0, 0, 0);
            bf16x8 bfB = *(const bf16x8*)(WB + (size_t)(cb * 16 + l16) * D_ + kk);
            accB[cb] = __builtin_amdgcn_mfma_f32_16x16x32_bf16(af, bfB, accB[cb], 0, 0, 0);
        }
    }
#pragma unroll
    for (int cb = 0; cb < 8; cb++) {
#pragma unroll
        for (int j = 0; j < 4; j++) {
            int r = row0 + kh * 4 + j;
            if (r < rows) {
                YA[(size_t)r * sA + cb * 16 + l16] = (__bf16)accA[cb][j];
                YB[(size_t)r * sB + cb * 16 + l16] = (__bf16)accB[cb][j];
            }
        }
    }
}

// ---------------- GEMM pair with independent gathered inputs: Yli = Xi[gi] @ Wli^T, Ylu = Xu[gu] @ Wlu^T ----------------
__global__ __launch_bounds__(256) void gemm_lilu(const float* __restrict__ Xi, const int* __restrict__ gi_,
                                                 const float* __restrict__ Xu, const int* __restrict__ gu_,
                                                 const __bf16* __restrict__ Wli, const __bf16* __restrict__ Wlu,
                                                 __bf16* __restrict__ Yli, __bf16* __restrict__ Ylu, int rows) {
    int lane = threadIdx.x & 63;
    int wave = threadIdx.x >> 6;
    int row0 = blockIdx.x * 64 + wave * 16;
    if (row0 >= rows) return;
    int l16 = lane & 15, kh = lane >> 4;
    int ar = row0 + l16;
    int arc = ar < rows ? ar : rows - 1;
    const float* arowA = Xi + (size_t)gi_[arc] * D_;
    const float* arowB = Xu + (size_t)gu_[arc] * D_;

    f32x4 accA[8] = {}, accB[8] = {};
#pragma unroll
    for (int k0 = 0; k0 < D_; k0 += 32) {
        int kk = k0 + kh * 8;
        float4 a0 = *(const float4*)(arowA + kk);
        float4 a1 = *(const float4*)(arowA + kk + 4);
        float4 b0 = *(const float4*)(arowB + kk);
        float4 b1 = *(const float4*)(arowB + kk + 4);
        bf16x8 afA, afB;
        afA[0] = (__bf16)a0.x; afA[1] = (__bf16)a0.y; afA[2] = (__bf16)a0.z; afA[3] = (__bf16)a0.w;
        afA[4] = (__bf16)a1.x; afA[5] = (__bf16)a1.y; afA[6] = (__bf16)a1.z; afA[7] = (__bf16)a1.w;
        afB[0] = (__bf16)b0.x; afB[1] = (__bf16)b0.y; afB[2] = (__bf16)b0.z; afB[3] = (__bf16)b0.w;
        afB[4] = (__bf16)b1.x; afB[5] = (__bf16)b1.y; afB[6] = (__bf16)b1.z; afB[7] = (__bf16)b1.w;
#pragma unroll
        for (int cb = 0; cb < 8; cb++) {
            bf16x8 bfA = *(const bf16x8*)(Wli + (size_t)(cb * 16 + l16) * D_ + kk);
            accA[cb] = __builtin_amdgcn_mfma_f32_16x16x32_bf16(afA, bfA, accA[cb], 0, 0, 0);
            bf16x8 bfB = *(const bf16x8*)(Wlu + (size_t)(cb * 16 + l16) * D_ + kk);
            accB[cb] = __builtin_amdgcn_mfma_f32_16x16x32_bf16(afB, bfB, accB[cb], 0, 0, 0);
        }
    }
#pragma unroll
    for (int cb = 0; cb < 8; cb++) {
#pragma unroll
        for (int j = 0; j < 4; j++) {
            int r = row0 + kh * 4 + j;
            if (r < rows) {
                Yli[(size_t)r * D_ + cb * 16 + l16] = (__bf16)accA[cb][j];
                Ylu[(size_t)r * D_ + cb * 16 + l16] = (__bf16)accB[cb][j];
            }
        }
    }
}

// ---------------- small GEMM: Y = (Xb @ P^T) * INV_SQRT_D ----------------
__global__ __launch_bounds__(256) void gemm_pvk(const __bf16* __restrict__ Xb, int xstride,
                                                const __bf16* __restrict__ Pb,
                                                float* __restrict__ Y, int rows, int ncols) {
    int lane = threadIdx.x & 63;
    int wave = threadIdx.x >> 6;
    int row0 = blockIdx.x * 64 + wave * 16;
    if (row0 >= rows) return;
    int l16 = lane & 15, kh = lane >> 4;
    int ar = row0 + l16;
    int arc = ar < rows ? ar : rows - 1;
    const __bf16* arow = Xb + (size_t)arc * xstride;

    f32x4 acc[4] = {};
#pragma unroll
    for (int k0 = 0; k0 < D_; k0 += 32) {
        int kk = k0 + kh * 8;
        bf16x8 af = *(const bf16x8*)(arow + kk);
#pragma unroll
        for (int cb = 0; cb < 4; cb++) {
            int br = cb * 16 + l16;
            if (br >= ncols) br = ncols - 1;
            bf16x8 bf = *(const bf16x8*)(Pb + (size_t)br * D_ + kk);
            acc[cb] = __builtin_amdgcn_mfma_f32_16x16x32_bf16(af, bf, acc[cb], 0, 0, 0);
        }
    }
#pragma unroll
    for (int cb = 0; cb < 4; cb++) {
        int col = cb * 16 + l16;
        if (col >= ncols) continue;
#pragma unroll
        for (int j = 0; j < 4; j++) {
            int r = row0 + kh * 4 + j;
            if (r < rows) Y[(size_t)r * ncols + col] = acc[cb][j] * INV_SQRT_D;
        }
    }
}

// ---------------- CSR build (combined users+items) ----------------
__global__ __launch_bounds__(256) void hist2(const int* __restrict__ eu, const int* __restrict__ ei,
                                             int* __restrict__ cnt_all, int nu, int E) {
    int e = blockIdx.x * 256 + threadIdx.x;
    if (e < E) {
        atomicAdd(&cnt_all[eu[e]], 1);
        atomicAdd(&cnt_all[nu + ei[e]], 1);
    }
}

__global__ __launch_bounds__(256) void scan_phaseA(const int* __restrict__ cnt, int* __restrict__ part, int n) {
    __shared__ int wsum[4];
    int t = threadIdx.x, lane = t & 63, w = t >> 6;
    int i0 = blockIdx.x * SCAN_TILE + t * SCAN_CH;
    int tot = 0;
#pragma unroll
    for (int j = 0; j < SCAN_CH; j++) tot += (i0 + j < n) ? cnt[i0 + j] : 0;
#pragma unroll
    for (int d = 32; d; d >>= 1) tot += __shfl_xor(tot, d);
    if (lane == 0) wsum[w] = tot;
    __syncthreads();
    if (t == 0) part[blockIdx.x] = wsum[0] + wsum[1] + wsum[2] + wsum[3];
}

__global__ __launch_bounds__(1024) void scan_phaseB(int* __restrict__ part, int nb,
                                                    int* __restrict__ off, int n) {
    __shared__ int wsum[16];
    int t = threadIdx.x, lane = t & 63, w = t >> 6;
    int v = (t < nb) ? part[t] : 0;
    int x = v;
#pragma unroll
    for (int d = 1; d < 64; d <<= 1) {
        int y = __shfl_up(x, d);
        if (lane >= d) x += y;
    }
    if (lane == 63) wsum[w] = x;
    __syncthreads();
    int wbase = 0;
    for (int ww = 0; ww < w; ww++) wbase += wsum[ww];
    if (t < nb) part[t] = wbase + x - v;
    if (t == 1023) off[n] = wbase + x;
}

__global__ __launch_bounds__(256) void scan_phaseC(const int* __restrict__ cnt, const int* __restrict__ part,
                                                   int* __restrict__ off, int* __restrict__ pos, int n) {
    __shared__ int wsum[4];
    int t = threadIdx.x, lane = t & 63, w = t >> 6;
    int i0 = blockIdx.x * SCAN_TILE + t * SCAN_CH;
    int loc[SCAN_CH];
    int tot = 0;
#pragma unroll
    for (int j = 0; j < SCAN_CH; j++) {
        int v = (i0 + j < n) ? cnt[i0 + j] : 0;
        loc[j] = tot; tot += v;
    }
    int x = tot;
#pragma unroll
    for (int d = 1; d < 64; d <<= 1) {
        int y = __shfl_up(x, d);
        if (lane >= d) x += y;
    }
    if (lane == 63) wsum[w] = x;
    __syncthreads();
    int wbase = 0;
    for (int ww = 0; ww < w; ww++) wbase += wsum[ww];
    int excl = part[blockIdx.x] + wbase + x - tot;
#pragma unroll
    for (int j = 0; j < SCAN_CH; j++) {
        if (i0 + j < n) { off[i0 + j] = excl + loc[j]; pos[i0 + j] = excl + loc[j]; }
    }
}

// scatter packed records: user slot gets {item, rui, riu, item_slot}; item slot gets {user, rui, riu, 0}
__global__ __launch_bounds__(256) void scatter2(const int* __restrict__ eu, const int* __restrict__ ei,
                                                const int* __restrict__ rui, const int* __restrict__ riu,
                                                int* __restrict__ pos_all, int4* __restrict__ recs,
                                                int nu, int E) {
    int e = blockIdx.x * 256 + threadIdx.x;
    if (e < E) {
        int u = eu[e], it = ei[e], r1 = rui[e], r2 = riu[e];
        int pi = atomicAdd(&pos_all[nu + it], 1);
        int pu = atomicAdd(&pos_all[u], 1);
        recs[pu] = make_int4(it, r1, r2, pi);
        recs[pi] = make_int4(u, r1, r2, 0);
    }
}

// ---------------- fused per-user: all 3 logit dots (um/li/lu in regs), 2x unrolled ----------------
__global__ __launch_bounds__(256) void user_fused(const int* __restrict__ off_all, const int4* __restrict__ recs,
                                                  const __bf16* __restrict__ i_rec,
                                                  const __bf16* __restrict__ u_rec,
                                                  const __bf16* __restrict__ li_t,
                                                  const __bf16* __restrict__ lu_t,
                                                  const __bf16* __restrict__ pKb,
                                                  const float* __restrict__ upv,
                                                  float2* __restrict__ mb_val,
                                                  float* __restrict__ hLu, float* __restrict__ hSu,
                                                  int nu, int umax) {
    int u = blockIdx.x * 4 + (threadIdx.x >> 6);
    if (u >= nu) return;
    int lane = threadIdx.x & 63;
    int g = lane >> 4, l16 = lane & 15;
    int off = off_all[u], n = off_all[u + 1] - off;
    if (n == 0) {
        if (lane < 16) {
            float4 z = make_float4(0.f, 0.f, 0.f, 0.f);
            ((float4*)(hLu + (size_t)u * D_ + l16 * 8))[0] = z;
            ((float4*)(hLu + (size_t)u * D_ + l16 * 8))[1] = z;
            ((float4*)(hSu + (size_t)u * D_ + l16 * 8))[0] = z;
            ((float4*)(hSu + (size_t)u * D_ + l16 * 8))[1] = z;
        }
        return;
    }
    float um8[8], li8[8], lu8[8];
    unpack8(((const bf16x8*)(u_rec + (size_t)u * 256))[l16], um8);
    unpack8(((const bf16x8*)(li_t + (size_t)u * D_))[l16], li8);
    unpack8(((const bf16x8*)(lu_t + (size_t)u * D_))[l16], lu8);
#pragma unroll
    for (int j = 0; j < 8; j++) { um8[j] *= INV_SQRT_D; li8[j] *= INV_SQRT_D; lu8[j] *= INV_SQRT_D; }
    const float* upv_row = upv + (size_t)u * umax;

    float s1 = 0.f, s2 = 0.f, a1[8] = {}, a2[8] = {};
    for (int i = g; i < n; i += 8) {
        int4 ra = recs[off + i];
        bool hb = (i + 4) < n;
        int4 rb = recs[off + (hb ? i + 4 : i)];
        const __bf16* pa = i_rec + (size_t)ra.x * 256;
        const __bf16* pb = i_rec + (size_t)rb.x * 256;
        bf16x8 vimA = ((const bf16x8*)pa)[l16];
        bf16x8 vmbA = ((const bf16x8*)(pa + 128))[l16];
        bf16x8 vpkA = ((const bf16x8*)(pKb + (size_t)ra.z * D_))[l16];
        bf16x8 vimB = ((const bf16x8*)pb)[l16];
        bf16x8 vmbB = ((const bf16x8*)(pb + 128))[l16];
        bf16x8 vpkB = ((const bf16x8*)(pKb + (size_t)rb.z * D_))[l16];
        float fimA[8], fmbA[8], fpkA[8], fimB[8], fmbB[8], fpkB[8];
        unpack8(vimA, fimA); unpack8(vmbA, fmbA); unpack8(vpkA, fpkA);
        unpack8(vimB, fimB); unpack8(vmbB, fmbB); unpack8(vpkB, fpkB);
        float d1a = 0.f, d2a = 0.f, d3a = 0.f, d1b = 0.f, d2b = 0.f, d3b = 0.f;
#pragma unroll
        for (int j = 0; j < 8; j++) {
            d1a = fmaf(um8[j], fimA[j], d1a);
            d2a = fmaf(li8[j], fimA[j], d2a);
            d3a = fmaf(lu8[j], fimA[j], d3a);
            d1b = fmaf(um8[j], fimB[j], d1b);
            d2b = fmaf(li8[j], fimB[j], d2b);
            d3b = fmaf(lu8[j], fimB[j], d3b);
        }
#pragma unroll
        for (int d = 1; d < 16; d <<= 1) {
            d1a += __shfl_xor(d1a, d); d2a += __shfl_xor(d2a, d); d3a += __shfl_xor(d3a, d);
            d1b += __shfl_xor(d1b, d); d2b += __shfl_xor(d2b, d); d3b += __shfl_xor(d3b, d);
        }
        if (l16 == 0) {
            mb_val[ra.w] = make_float2(d1a, d3a);
            if (hb) mb_val[rb.w] = make_float2(d1b, d3b);
        }
        float w1a = __expf(d1a + upv_row[ra.y]);
        float w2a = __expf(d2a);
        float w1b = hb ? __expf(d1b + upv_row[rb.y]) : 0.f;
        float w2b = hb ? __expf(d2b) : 0.f;
        s1 += w1a + w1b; s2 += w2a + w2b;
#pragma unroll
        for (int j = 0; j < 8; j++) {
            a1[j] = fmaf(w1a, fmbA[j] + fpkA[j], fmaf(w1b, fmbB[j] + fpkB[j], a1[j]));
            a2[j] = fmaf(w2a, fimA[j], fmaf(w2b, fimB[j], a2[j]));
        }
    }
    // merge 4 groups
#pragma unroll
    for (int d = 16; d < 64; d <<= 1) {
        s1 += __shfl_xor(s1, d); s2 += __shfl_xor(s2, d);
#pragma unroll
        for (int j = 0; j < 8; j++) {
            a1[j] += __shfl_xor(a1[j], d);
            a2[j] += __shfl_xor(a2[j], d);
        }
    }
    if (lane < 16) {
        float inv1 = 1.f / s1, inv2 = 1.f / s2;
        ((float4*)(hLu + (size_t)u * D_ + l16 * 8))[0] = make_float4(a1[0]*inv1, a1[1]*inv1, a1[2]*inv1, a1[3]*inv1);
        ((float4*)(hLu + (size_t)u * D_ + l16 * 8))[1] = make_float4(a1[4]*inv1, a1[5]*inv1, a1[6]*inv1, a1[7]*inv1);
        ((float4*)(hSu + (size_t)u * D_ + l16 * 8))[0] = make_float4(a2[0]*inv2+1.f, a2[1]*inv2+1.f, a2[2]*inv2+1.f, a2[3]*inv2+1.f);
        ((float4*)(hSu + (size_t)u * D_ + l16 * 8))[1] = make_float4(a2[4]*inv2+1.f, a2[5]*inv2+1.f, a2[6]*inv2+1.f, a2[7]*inv2+1.f);
    }
}

// ---------------- fused per-item: no dots; logits from coalesced mb_val + ipk, 2x unrolled ----------------
__global__ __launch_bounds__(256) void item_fused(const int* __restrict__ off_all, const int4* __restrict__ recs,
                                                  const __bf16* __restrict__ u_rec,
                                                  const __bf16* __restrict__ pVb,
                                                  const float* __restrict__ ipk,
                                                  const float2* __restrict__ mb_val,
                                                  float* __restrict__ hLi, float* __restrict__ hSi,
                                                  int nu, int ni, int imax) {
    int it = blockIdx.x * 4 + (threadIdx.x >> 6);
    if (it >= ni) return;
    int lane = threadIdx.x & 63;
    int g = lane >> 4, l16 = lane & 15;
    int off = off_all[nu + it], n = off_all[nu + it + 1] - off;
    if (n == 0) {
        if (lane < 16) {
            float4 z = make_float4(0.f, 0.f, 0.f, 0.f);
            ((float4*)(hLi + (size_t)it * D_ + l16 * 8))[0] = z;
            ((float4*)(hLi + (size_t)it * D_ + l16 * 8))[1] = z;
            ((float4*)(hSi + (size_t)it * D_ + l16 * 8))[0] = z;
            ((float4*)(hSi + (size_t)it * D_ + l16 * 8))[1] = z;
        }
        return;
    }
    const float* ipk_row = ipk + (size_t)it * imax;

    float s1 = 0.f, s2 = 0.f, a1[8] = {}, a2[8] = {};
    for (int i = g; i < n; i += 8) {
        int4 ra = recs[off + i];
        bool hb = (i + 4) < n;
        int4 rb = recs[off + (hb ? i + 4 : i)];
        float2 ma = mb_val[off + i];
        float2 mbv = hb ? mb_val[off + i + 4] : make_float2(0.f, 0.f);
        const __bf16* pa = u_rec + (size_t)ra.x * 256;
        const __bf16* pb = u_rec + (size_t)rb.x * 256;
        bf16x8 vumA  = ((const bf16x8*)pa)[l16];
        bf16x8 vmbA  = ((const bf16x8*)(pa + 128))[l16];
        bf16x8 vpvA  = ((const bf16x8*)(pVb + (size_t)ra.y * D_))[l16];
        bf16x8 vumB  = ((const bf16x8*)pb)[l16];
        bf16x8 vmbB  = ((const bf16x8*)(pb + 128))[l16];
        bf16x8 vpvB  = ((const bf16x8*)(pVb + (size_t)rb.y * D_))[l16];
        float fumA[8], fmbA[8], fpvA[8], fumB[8], fmbB[8], fpvB[8];
        unpack8(vumA, fumA); unpack8(vmbA, fmbA); unpack8(vpvA, fpvA);
        unpack8(vumB, fumB); unpack8(vmbB, fmbB); unpack8(vpvB, fpvB);
        float w1a = __expf(ma.x + ipk_row[ra.z]);
        float w2a = __expf(ma.y);
        float w1b = hb ? __expf(mbv.x + ipk_row[rb.z]) : 0.f;
        float w2b = hb ? __expf(mbv.y) : 0.f;
        s1 += w1a + w1b; s2 += w2a + w2b;
#pragma unroll
        for (int j = 0; j < 8; j++) {
            a1[j] = fmaf(w1a, fmbA[j] + fpvA[j], fmaf(w1b, fmbB[j] + fpvB[j], a1[j]));
            a2[j] = fmaf(w2a, fumA[j], fmaf(w2b, fumB[j], a2[j]));
        }
    }
#pragma unroll
    for (int d = 16; d < 64; d <<= 1) {
        s1 += __shfl_xor(s1, d); s2 += __shfl_xor(s2, d);
#pragma unroll
        for (int j = 0; j < 8; j++) {
            a1[j] += __shfl_xor(a1[j], d);
            a2[j] += __shfl_xor(a2[j], d);
        }
    }
    if (lane < 16) {
        float inv1 = 1.f / s1, inv2 = 1.f / s2;
        ((float4*)(hLi + (size_t)it * D_ + l16 * 8))[0] = make_float4(a1[0]*inv1, a1[1]*inv1, a1[2]*inv1, a1[3]*inv1);
        ((float4*)(hLi + (size_t)it * D_ + l16 * 8))[1] = make_float4(a1[4]*inv1, a1[5]*inv1, a1[6]*inv1, a1[7]*inv1);
        ((float4*)(hSi + (size_t)it * D_ + l16 * 8))[0] = make_float4(a2[0]*inv2+1.f, a2[1]*inv2+1.f, a2[2]*inv2+1.f, a2[3]*inv2+1.f);
        ((float4*)(hSi + (size_t)it * D_ + l16 * 8))[1] = make_float4(a2[4]*inv2+1.f, a2[5]*inv2+1.f, a2[6]*inv2+1.f, a2[7]*inv2+1.f);
    }
}

extern "C" void kernel_launch(void* const* d_in, const int* in_sizes, int n_in,
                              void* d_out, int out_size, void* d_ws, size_t ws_size,
                              hipStream_t stream) {
    (void)n_in; (void)out_size; (void)ws_size;
    const float* u_emb = (const float*)d_in[0];
    const float* i_emb = (const float*)d_in[1];
    const int* edge_u = (const int*)d_in[2];
    const int* edge_i = (const int*)d_in[3];
    const int* rui = (const int*)d_in[4];
    const int* riu = (const int*)d_in[5];
    const int* last_u_items = (const int*)d_in[6];
    const int* last_i_users = (const int*)d_in[7];
    const float* W1  = (const float*)d_in[8];
    const float* W2  = (const float*)d_in[9];
    const float* W1b = (const float*)d_in[10];
    const float* W2b = (const float*)d_in[11];
    const float* W3  = (const float*)d_in[12];
    const float* W4  = (const float*)d_in[13];
    const float* pV  = (const float*)d_in[14];
    const float* pK  = (const float*)d_in[15];
    const float* last_user_table = (const float*)d_in[16];
    const float* last_item_table = (const float*)d_in[17];

    const int NU = in_sizes[0] / D_;
    const int NI = in_sizes[1] / D_;
    const int E  = in_sizes[2];
    const int UMAXr = in_sizes[14] / D_;
    const int IMAXr = in_sizes[15] / D_;
    const int NSEG = NU + NI;

    size_t cur = 0;
    auto alloc = [&](size_t bytes) -> void* {
        void* p = (char*)d_ws + cur;
        cur += (bytes + 255) & ~(size_t)255;
        return p;
    };

    __bf16* Wb    = (__bf16*)alloc(6 * 16384 * sizeof(__bf16));
    __bf16* pVb   = (__bf16*)alloc((size_t)UMAXr * D_ * 2);
    __bf16* pKb   = (__bf16*)alloc((size_t)IMAXr * D_ * 2);
    __bf16* i_rec = (__bf16*)alloc((size_t)NI * 256 * 2);   // {im, imb}
    __bf16* u_rec = (__bf16*)alloc((size_t)NU * 256 * 2);   // {um, umb}
    __bf16* li_bf = (__bf16*)alloc((size_t)NU * D_ * 2);
    __bf16* lu_bf = (__bf16*)alloc((size_t)NU * D_ * 2);
    float* upv    = (float*)alloc((size_t)NU * UMAXr * 4);
    float* ipk    = (float*)alloc((size_t)NI * IMAXr * 4);
    float2* mb_val = (float2*)alloc((size_t)2 * E * 8);
    int4* recs    = (int4*)alloc((size_t)2 * E * 16);
    int* cnt_all  = (int*)alloc((size_t)NSEG * 4);
    int* off_all  = (int*)alloc((size_t)(NSEG + 1) * 4);
    int* pos_all  = (int*)alloc((size_t)NSEG * 4);
    int* parts    = (int*)alloc(1024 * 4);

    float* out = (float*)d_out;
    float* hLu = out;
    float* hSu = out + (size_t)NU * D_;
    float* hLi = out + (size_t)2 * NU * D_;
    float* hSi = out + (size_t)2 * NU * D_ + (size_t)NI * D_;

    // weights -> bf16
    W6 w6;
    w6.p[0] = W1; w6.p[1] = W2; w6.p[2] = W1b; w6.p[3] = W2b; w6.p[4] = W3; w6.p[5] = W4;
    cvt_weights<<<(6 * 16384 + 255) / 256, 256, 0, stream>>>(w6, Wb);
    cvt2<<<(UMAXr * D_ + 255) / 256, 256, 0, stream>>>(pV, pK, pVb, pKb, UMAXr * D_);

    // CSR build (combined users+items, multi-block scan, packed records)
    hipMemsetAsync(cnt_all, 0, (size_t)NSEG * 4, stream);
    hist2<<<(E + 255) / 256, 256, 0, stream>>>(edge_u, edge_i, cnt_all, NU, E);
    int nb = (NSEG + SCAN_TILE - 1) / SCAN_TILE;
    scan_phaseA<<<nb, 256, 0, stream>>>(cnt_all, parts, NSEG);
    scan_phaseB<<<1, 1024, 0, stream>>>(parts, nb, off_all, NSEG);
    scan_phaseC<<<nb, 256, 0, stream>>>(cnt_all, parts, off_all, pos_all, NSEG);
    scatter2<<<(E + 255) / 256, 256, 0, stream>>>(edge_u, edge_i, rui, riu, pos_all, recs, NU, E);

    // GEMMs into packed records
    int gu = (NU + 63) / 64, gi = (NI + 63) / 64;
    gemm_dual<<<gi, 256, 0, stream>>>(i_emb, Wb + 0 * 16384, Wb + 2 * 16384,
                                      i_rec + 0, 256, i_rec + 128, 256, NI);     // im, imb
    gemm_dual<<<gu, 256, 0, stream>>>(u_emb, Wb + 1 * 16384, Wb + 3 * 16384,
                                      u_rec + 0, 256, u_rec + 128, 256, NU);     // um, umb
    gemm_lilu<<<gu, 256, 0, stream>>>(last_item_table, last_u_items, last_user_table, last_i_users,
                                      Wb + 4 * 16384, Wb + 5 * 16384, li_bf, lu_bf, NU); // li, lu

    // positional-dot tables (pre-scaled by 1/sqrt(D))
    gemm_pvk<<<gu, 256, 0, stream>>>(u_rec, 256, pVb, upv, NU, UMAXr);
    gemm_pvk<<<gi, 256, 0, stream>>>(i_rec, 256, pKb, ipk, NI, IMAXr);

    // fused softmax + message passing (user first: produces mb_val for item pass)
    user_fused<<<(NU + 3) / 4, 256, 0, stream>>>(off_all, recs, i_rec, u_rec, li_bf, lu_bf,
                                                 pKb, upv, mb_val, hLu, hSu, NU, UMAXr);
    item_fused<<<(NI + 3) / 4, 256, 0, stream>>>(off_all, recs, u_rec, pVb, ipk, mb_val,
                                                 hLi, hSi, NU, NI, IMAXr);
}